// Round 7
// baseline (187.278 us; speedup 1.0000x reference)
//
#include <hip/hip_runtime.h>

// Transposed conv (stride 2, 4x4, pad 2) as bf16 MFMA implicit GEMM, v6.
// x: (32,256,32,32) f32, W: (128,256,4,4) OIHW f32, b: (128,), out: (32,128,64,64) f32
// y[n,o,2a+pi,2b+pj] = bias[o] + sum_{c,du,dv} W[o,c,pi+2du,pj+2dv] * x[n,c,a+pi-1+du,b+pj-1+dv]
//
// v6 vs v5: (1) 3-buffer W LDS (50 KB) -> 3 blocks/CU (3 waves/SIMD, +50% TLP),
// distance-2 prefetch, steady vmcnt(8); (2) s_setprio around MFMA cluster (T5 —
// co-resident blocks now at different phases); (3) epilogue bank-conflict fix:
// write rows remapped so lg-quarters hit bank offsets 0/8/16/24, reads as
// float2 pairs covering all 32 banks per instr.

typedef float  f32x4  __attribute__((ext_vector_type(4)));
typedef short  short8 __attribute__((ext_vector_type(8)));
typedef unsigned short ushort4v __attribute__((ext_vector_type(4)));
typedef unsigned short ushort8v __attribute__((ext_vector_type(8)));

__device__ __forceinline__ unsigned short f2bf(float f) {
    unsigned u = __builtin_bit_cast(unsigned, f);
    u += 0x7fffu + ((u >> 16) & 1u);          // RNE (inputs finite)
    return (unsigned short)(u >> 16);
}

__device__ __forceinline__ void ld_lds16(const unsigned short* g, unsigned short* l) {
    __builtin_amdgcn_global_load_lds(
        (const __attribute__((address_space(1))) unsigned int*)g,
        (__attribute__((address_space(3))) unsigned int*)l,
        16, 0, 0);
}

// ---------------- layout constants (ushort units) ----------------
#define XP_U 288                 // per u' row: 36 v' * 8 c
#define XP_G 9792                // per (n,g): 34 * XP_U
#define XP_N 313344              // per n: 32 g * XP_G
#define WP_G 8192                // per (pi,g): 2 pj * 4 sub * 128 o * 8 c
#define WP_PI 262144             // 32 g * WP_G
#define WROW 1040                // LDS sh-stride per (pj,sub) row
#define WBUFS 8320               // 8 * WROW per buffer

// Wp2[pi][g][pj][sub][o][c8] = bf16(W[o][g*8+c8][pi+2du][pj+2dv]), sub=2du+dv
__global__ __launch_bounds__(256) void prepack_w2(const float* __restrict__ W,
                                                  unsigned short* __restrict__ wp) {
    int t = blockIdx.x * 256 + threadIdx.x;   // (o,c) in [0, 32768)
    int o = t >> 8, c = t & 255;
    int g = c >> 3, c8 = c & 7;
    const float4* src = (const float4*)(W + (size_t)(o * 256 + c) * 16);
    float4 q0 = src[0], q1 = src[1], q2 = src[2], q3 = src[3];
    float rows[4][4] = {{q0.x,q0.y,q0.z,q0.w},{q1.x,q1.y,q1.z,q1.w},
                        {q2.x,q2.y,q2.z,q2.w},{q3.x,q3.y,q3.z,q3.w}};
    #pragma unroll
    for (int pi = 0; pi < 2; ++pi)
    #pragma unroll
    for (int pj = 0; pj < 2; ++pj)
    #pragma unroll
    for (int du = 0; du < 2; ++du)
    #pragma unroll
    for (int dv = 0; dv < 2; ++dv)
        wp[pi*WP_PI + g*WP_G + pj*4096 + (du*2+dv)*1024 + o*8 + c8] =
            f2bf(rows[pi+2*du][pj+2*dv]);
}

// xp[n][g][u'][v'][c8] = bf16(x[n][g*8+c8][u'-1][v'-1]); u'/v' out of range -> 0.
__global__ __launch_bounds__(256) void prepack_x(const float* __restrict__ x,
                                                 unsigned short* __restrict__ xp) {
    __shared__ unsigned short xt[256 * 32];   // [c][v] bf16, 16 KB
    const int tid = threadIdx.x;
    const int up  = blockIdx.x;               // u' in [0,34)
    const int n   = blockIdx.y;
    const bool interior = (up >= 1 && up <= 32);

    if (interior) {
        const int u = up - 1;
        #pragma unroll
        for (int k = 0; k < 8; ++k) {
            int idx4 = tid + k * 256;          // [0,2048) float4 units
            int c = idx4 >> 3, v4 = idx4 & 7;
            float4 val = *(const float4*)(x + ((size_t)(n*256 + c)*32 + u)*32 + v4*4);
            ushort4v s = { f2bf(val.x), f2bf(val.y), f2bf(val.z), f2bf(val.w) };
            *(ushort4v*)&xt[c*32 + v4*4] = s;
        }
        __syncthreads();
    }

    #pragma unroll
    for (int s = 0; s < 5; ++s) {
        int id = tid + s * 256;                // (g, v') in [0, 32*36)
        if (id < 1152) {
            int g = id / 36, vp = id % 36;
            ushort8v o8 = {0,0,0,0,0,0,0,0};
            if (interior && vp >= 1 && vp <= 32) {      // v = vp-1 in [0,32)
                #pragma unroll
                for (int e = 0; e < 8; ++e)
                    o8[e] = xt[(g*8 + e)*32 + (vp - 1)];
            }
            *(ushort8v*)&xp[(size_t)n*XP_N + g*XP_G + up*XP_U + vp*8] = o8;
        }
    }
}

// Main: grid 512 = (pi, aq in [0,8), n) XCD-swizzled; 256 thr = 4 waves (pjw, half).
// Block tile: 128 o x (4 arows x 32 b x 2 pj). Wave: 128 o x 64 px -> 8x4 MFMA tiles.
__global__ __launch_bounds__(256, 3) void tconv_main(
    const unsigned short* __restrict__ xp,
    const unsigned short* __restrict__ wp,
    const float* __restrict__ bias,
    float* __restrict__ out)
{
    // W only: 3 buffers x 8320 sh = 24960 sh = 49920 B  -> 3 blocks/CU
    __shared__ __align__(16) unsigned short lds[24960];
    unsigned short* wsh0 = lds;

    const int tid  = threadIdx.x;
    const int lane = tid & 63;
    const int w    = tid >> 6;       // wave 0..3
    const int pjw  = w >> 1;
    const int half = w & 1;
    const int lg   = lane >> 4;      // sub = (du,dv)
    const int ln   = lane & 15;
    const int du   = lg >> 1, dv = lg & 1;

    const int bid = blockIdx.x;
    const int wg  = (bid & 7) * 64 + (bid >> 3);   // XCD swizzle (512 % 8 == 0)
    const int n   = wg >> 4;
    const int aq  = (wg >> 1) & 7;
    const int pi  = wg & 1;
    const int a0  = aq * 4;

    const unsigned short* xpb = xp + (size_t)n * XP_N + (a0 + pi) * XP_U;
    const unsigned short* wpb = wp + pi * WP_PI;

    // per-lane fragment offsets (static after unroll)
    int xoff[4];
    #pragma unroll
    for (int jj = 0; jj < 4; ++jj) {
        int rr = half * 2 + (jj >> 1) + du;
        int vv = (jj & 1) * 16 + ln + pjw + dv;
        xoff[jj] = rr * XP_U + vv * 8;
    }
    const int wfoff = (pjw * 4 + lg) * WROW + ln * 8;

    f32x4 acc[8][4];
    #pragma unroll
    for (int i = 0; i < 8; ++i)
        #pragma unroll
        for (int jj = 0; jj < 4; ++jj)
            acc[i][jj] = (f32x4){0.f, 0.f, 0.f, 0.f};

    short8 xA[4], xB[4];

#define STAGE_W(CH, WBUF)                                                    \
    { const unsigned short* ws_ = wpb + (size_t)(CH) * WP_G;                 \
      unsigned short* wd_ = wsh0 + (WBUF) * WBUFS;                           \
      _Pragma("unroll")                                                      \
      for (int s_ = 0; s_ < 4; ++s_) {                                       \
          int r_ = w * 2 + (s_ >> 1), h_ = s_ & 1;                           \
          ld_lds16(ws_ + r_ * 1024 + h_ * 512 + lane * 8,                    \
                   wd_ + r_ * WROW + h_ * 512); } }

#define LOAD_X(CH, XS)                                                      \
    { const unsigned short* xs_ = xpb + (size_t)(CH) * XP_G;                 \
      _Pragma("unroll")                                                      \
      for (int jj_ = 0; jj_ < 4; ++jj_)                                      \
          XS[jj_] = *(const short8*)(xs_ + xoff[jj_]); }

// Body: wait vmcnt(VMN); barrier; [issue W(CH+2)->SBUF]; MFMA from BUF;
// [issue x(CH+2) into XS after consumption]
#define CHUNK(BUF, SBUF, XS, CH, VMN, DO_W, DO_X)                            \
    {                                                                        \
        __builtin_amdgcn_sched_barrier(0);                                   \
        asm volatile("s_waitcnt vmcnt(" #VMN ")" ::: "memory");              \
        __builtin_amdgcn_s_barrier();                                        \
        __builtin_amdgcn_sched_barrier(0);                                   \
        if (DO_W) STAGE_W((CH) + 2, SBUF);                                   \
        const unsigned short* wb_ = wsh0 + (BUF) * WBUFS + wfoff;            \
        __builtin_amdgcn_s_setprio(1);                                       \
        _Pragma("unroll")                                                    \
        for (int i_ = 0; i_ < 8; ++i_) {                                     \
            short8 av_ = *(const short8*)&wb_[i_ * 128];                     \
            _Pragma("unroll")                                                \
            for (int jj_ = 0; jj_ < 4; ++jj_)                                \
                acc[i_][jj_] = __builtin_amdgcn_mfma_f32_16x16x32_bf16(      \
                    av_, XS[jj_], acc[i_][jj_], 0, 0, 0);                    \
        }                                                                    \
        __builtin_amdgcn_s_setprio(0);                                       \
        if (DO_X) LOAD_X((CH) + 2, XS);                                      \
    }

    // Prologue ledger: [W0, x0, W1, x1] -> first wait vmcnt(8) retires W0,x0.
    STAGE_W(0, 0);
    __builtin_amdgcn_sched_barrier(0);
    LOAD_X(0, xA);
    __builtin_amdgcn_sched_barrier(0);
    STAGE_W(1, 1);
    __builtin_amdgcn_sched_barrier(0);
    LOAD_X(1, xB);
    __builtin_amdgcn_sched_barrier(0);

    // Steady state: chunk ch consumes buf[ch%3], stages W(ch+2)->buf[(ch+2)%3]
    // (== buf[(ch-1)%3], freed: all waves' ch-1 LDS reads completed into regs
    // before they passed barrier(ch)). x ping-pong distance 2.
    for (int c6 = 0; c6 < 30; c6 += 6) {
        CHUNK(0, 2, xA, c6 + 0, 8, 1, 1);
        CHUNK(1, 0, xB, c6 + 1, 8, 1, 1);
        CHUNK(2, 1, xA, c6 + 2, 8, 1, 1);
        CHUNK(0, 2, xB, c6 + 3, 8, 1, 1);
        CHUNK(1, 0, xA, c6 + 4, 8, 1, 1);
        CHUNK(2, 1, xB, c6 + 5, 8, 1, 1);
    }
    // Tail: queue at ch=30 is [W30,x30,W31,x31] -> vmcnt(8); at 31 -> vmcnt(4).
    CHUNK(0, 2, xA, 30, 8, 0, 0);
    CHUNK(1, 0, xB, 31, 4, 0, 0);

#undef CHUNK
#undef LOAD_X
#undef STAGE_W

    // Epilogue: LDS transpose -> coalesced float4 stores.
    // epi rows: row_w = (r*4+lg)*8 + ar*2 + pjw  (o_l' = r*4+lg).
    // lg-quarters of one store differ by 8 rows -> bank starts 0/8/16/24:
    // conflict-free. Reads: float2 pairs cover all 32 banks per instr.
    float* epi = (float*)lds;
    #pragma unroll
    for (int i = 0; i < 8; ++i) {
        __syncthreads();
        f32x4 bv = *(const f32x4*)&bias[i * 16 + lg * 4];
        #pragma unroll
        for (int jj = 0; jj < 4; ++jj) {
            int ar = half * 2 + (jj >> 1);
            int b  = (jj & 1) * 16 + ln;
            #pragma unroll
            for (int r = 0; r < 4; ++r)
                epi[((r * 4 + lg) * 8 + ar * 2 + pjw) * 33 + b] = acc[i][jj][r] + bv[r];
        }
        __syncthreads();
        #pragma unroll
        for (int k = 0; k < 4; ++k) {
            int f    = tid + k * 256;    // [0,1024) float4-store ids
            int row  = f >> 4;           // o_l'(row>>2) x ar(row&3)
            int q    = f & 15;
            float2 A = *(const float2*)&epi[(row * 2 + 0) * 33 + q * 2];
            float2 B = *(const float2*)&epi[(row * 2 + 1) * 33 + q * 2];
            float4 v = { A.x, B.x, A.y, B.y };
            int olp   = row >> 2;        // o_l' = r*4 + lg
            int o     = i * 16 + ((olp & 3) << 2) + (olp >> 2);   // o_l = lg*4+r
            int i_out = 2 * (a0 + (row & 3)) + pi;
            *(float4*)&out[(((size_t)n * 128 + o) * 64 + i_out) * 64 + q * 4] = v;
        }
    }
}

// =================== fallback: round-2 kernel (proven) ===================
__global__ __launch_bounds__(256) void prepack_w(const float* __restrict__ W,
                                                 unsigned short* __restrict__ Wp) {
    int t = blockIdx.x * 256 + threadIdx.x;
    int o = t >> 8, c = t & 255;
    const float4* src = (const float4*)(W + (size_t)(o * 256 + c) * 16);
    float4 q0 = src[0], q1 = src[1], q2 = src[2], q3 = src[3];
    float rows[4][4] = {{q0.x,q0.y,q0.z,q0.w},{q1.x,q1.y,q1.z,q1.w},
                        {q2.x,q2.y,q2.z,q2.w},{q3.x,q3.y,q3.z,q3.w}};
    #pragma unroll
    for (int pi = 0; pi < 2; ++pi)
    #pragma unroll
    for (int pj = 0; pj < 2; ++pj)
    #pragma unroll
    for (int du = 0; du < 2; ++du)
    #pragma unroll
    for (int dv = 0; dv < 2; ++dv)
        Wp[((((pi*2+pj)*4 + du*2+dv)*128 + o)*256) + c] = f2bf(rows[pi+2*du][pj+2*dv]);
}

template<bool PRE>
__global__ __launch_bounds__(512, 2) void tconv_mfma(
    const float* __restrict__ x, const float* __restrict__ W,
    const unsigned short* __restrict__ Wp, const float* __restrict__ bias,
    float* __restrict__ out)
{
    __shared__ __align__(16) unsigned short xsh[2][9 * 34 * 8];
    __shared__ __align__(16) unsigned short wsh[2][2 * 4 * 128 * 8];

    const int tid = threadIdx.x;
    const int bid = blockIdx.x;
    const int pi  = bid & 1;
    const int aq  = (bid >> 1) & 3;
    const int n   = bid >> 3;
    const int a0  = aq * 8;
    const int u0  = a0 + pi - 1;

    const int l   = tid & 63;
    const int w   = tid >> 6;
    const int pjw = w >> 2;
    const int q   = w & 3;
    const int lg  = l >> 4;
    const int ln  = l & 15;

    const int sv = tid & 31;
    const int sg = tid >> 5;

    f32x4 acc[8][4];
    #pragma unroll
    for (int i = 0; i < 8; ++i)
        #pragma unroll
        for (int jj = 0; jj < 4; ++jj)
            acc[i][jj] = (f32x4){0.f, 0.f, 0.f, 0.f};

    float    xv[5];
    ushort4v wv[4];
    float4   wa[2], wb[2];

    auto stage_load = [&](int ch) {
        const int c0 = ch * 8;
        #pragma unroll
        for (int s = 0; s < 5; ++s) {
            int p = sg * 5 + s;
            if (p < 72) {
                int c = p & 7, rr = p >> 3;
                int u = u0 + rr;
                xv[s] = ((unsigned)u < 32u)
                      ? x[((n*256 + c0 + c)*32 + u)*32 + sv] : 0.f;
            }
        }
        if (PRE) {
            #pragma unroll
            for (int k = 0; k < 4; ++k) {
                int uu = tid + k * 512;
                int chalf = uu & 1, o = (uu >> 1) & 127;
                int sub = (uu >> 8) & 3, pjq = (uu >> 10) & 1;
                wv[k] = *(const ushort4v*)&Wp[(((pi*2 + pjq)*4 + sub)*128 + o)*256
                                              + c0 + chalf*4];
            }
        } else {
            #pragma unroll
            for (int k = 0; k < 2; ++k) {
                int pr = tid + k * 512;
                int o = pr >> 3, c = pr & 7;
                const float* base = W + ((o*256 + c0 + c) << 4) + pi*4;
                wa[k] = *(const float4*)base;
                wb[k] = *(const float4*)(base + 8);
            }
        }
    };

    auto stage_write = [&](int buf) {
        #pragma unroll
        for (int s = 0; s < 5; ++s) {
            int p = sg * 5 + s;
            if (p < 72) {
                int c = p & 7, rr = p >> 3;
                xsh[buf][(rr*34 + sv + 1)*8 + c] = f2bf(xv[s]);
            }
        }
        if (tid < 144) {
            int pr = tid >> 1;
            int rr = pr >> 3, c = pr & 7;
            int cw = (tid & 1) * 33;
            xsh[buf][(rr*34 + cw)*8 + c] = 0;
        }
        if (PRE) {
            #pragma unroll
            for (int k = 0; k < 4; ++k) {
                int uu = tid + k * 512;
                int chalf = uu & 1, o = (uu >> 1) & 127;
                int sub = (uu >> 8) & 3, pjq = (uu >> 10) & 1;
                *(ushort4v*)&wsh[buf][(((pjq*4 + sub)*128 + o)*8) + chalf*4] = wv[k];
            }
        } else {
            #pragma unroll
            for (int k = 0; k < 2; ++k) {
                int pr = tid + k * 512;
                int o = pr >> 3, c = pr & 7;
                float ra[4] = {wa[k].x, wa[k].y, wa[k].z, wa[k].w};
                float rb[4] = {wb[k].x, wb[k].y, wb[k].z, wb[k].w};
                #pragma unroll
                for (int pj2 = 0; pj2 < 2; ++pj2)
                #pragma unroll
                for (int duu = 0; duu < 2; ++duu)
                #pragma unroll
                for (int dvv = 0; dvv < 2; ++dvv) {
                    float val = duu ? rb[pj2 + 2*dvv] : ra[pj2 + 2*dvv];
                    wsh[buf][(((pj2*4 + duu*2 + dvv)*128 + o)*8) + c] = f2bf(val);
                }
            }
        }
    };

    stage_load(0);
    stage_write(0);
    __syncthreads();

    for (int ch = 0; ch < 32; ++ch) {
        const int cur = ch & 1;
        if (ch + 1 < 32) stage_load(ch + 1);

        short8 bfr[4];
        #pragma unroll
        for (int jj = 0; jj < 4; ++jj) {
            int arow = q*2 + (jj >> 1);
            int b    = (jj & 1)*16 + ln;
            int rr   = arow + (lg >> 1);
            int cw   = b + pjw + (lg & 1);
            bfr[jj]  = *(const short8*)&xsh[cur][(rr*34 + cw)*8];
        }
        #pragma unroll
        for (int i = 0; i < 8; ++i) {
            short8 av = *(const short8*)&wsh[cur][((pjw*4 + lg)*128 + i*16 + ln)*8];
            #pragma unroll
            for (int jj = 0; jj < 4; ++jj)
                acc[i][jj] = __builtin_amdgcn_mfma_f32_16x16x32_bf16(
                                 av, bfr[jj], acc[i][jj], 0, 0, 0);
        }

        if (ch + 1 < 32) stage_write(cur ^ 1);
        __syncthreads();
    }

    #pragma unroll
    for (int i = 0; i < 8; ++i) {
        const f32x4 bv = *(const f32x4*)&bias[i*16 + lg*4];
        #pragma unroll
        for (int jj = 0; jj < 4; ++jj) {
            int arow  = q*2 + (jj >> 1);
            int b     = (jj & 1)*16 + ln;
            int i_out = 2*(a0 + arow) + pi;
            int j_out = 2*b + pjw;
            int o0    = i*16 + lg*4;
            int base  = ((n*128 + o0)*64 + i_out)*64 + j_out;
            #pragma unroll
            for (int r = 0; r < 4; ++r)
                out[base + r*4096] = acc[i][jj][r] + bv[r];
        }
    }
}

extern "C" void kernel_launch(void* const* d_in, const int* in_sizes, int n_in,
                              void* d_out, int out_size, void* d_ws, size_t ws_size,
                              hipStream_t stream) {
    const float* x    = (const float*)d_in[0];
    const float* W    = (const float*)d_in[1];
    const float* bias = (const float*)d_in[2];
    float* out        = (float*)d_out;

    const size_t wp2_bytes = (size_t)2 * WP_PI * 2;          // 1 MB
    const size_t xp_bytes  = (size_t)32 * XP_N * 2;          // ~20 MB
    if (ws_size >= wp2_bytes + xp_bytes) {
        unsigned short* wp2 = (unsigned short*)d_ws;
        unsigned short* xpp = (unsigned short*)((char*)d_ws + wp2_bytes);
        prepack_w2<<<128, 256, 0, stream>>>(W, wp2);
        prepack_x<<<dim3(34, 32), 256, 0, stream>>>(x, xpp);
        tconv_main<<<512, 256, 0, stream>>>(xpp, wp2, bias, out);
    } else if (ws_size >= (size_t)4*4*128*256*2) {
        unsigned short* Wp = (unsigned short*)d_ws;
        prepack_w<<<128, 256, 0, stream>>>(W, Wp);
        tconv_mfma<true><<<256, 512, 0, stream>>>(x, W, Wp, bias, out);
    } else {
        tconv_mfma<false><<<256, 512, 0, stream>>>(x, W, nullptr, bias, out);
    }
}

// Round 8
// 187.001 us; speedup vs baseline: 1.0015x; 1.0015x over previous
//
#include <hip/hip_runtime.h>

// Transposed conv (stride 2, 4x4, pad 2) as bf16 MFMA implicit GEMM, v6.
// x: (32,256,32,32) f32, W: (128,256,4,4) OIHW f32, b: (128,), out: (32,128,64,64) f32
// y[n,o,2a+pi,2b+pj] = bias[o] + sum_{c,du,dv} W[o,c,pi+2du,pj+2dv] * x[n,c,a+pi-1+du,b+pj-1+dv]
//
// v6 vs v5: (1) 3-buffer W LDS (50 KB) -> 3 blocks/CU (3 waves/SIMD, +50% TLP),
// distance-2 prefetch, steady vmcnt(8); (2) s_setprio around MFMA cluster (T5 —
// co-resident blocks now at different phases); (3) epilogue bank-conflict fix:
// write rows remapped so lg-quarters hit bank offsets 0/8/16/24, reads as
// float2 pairs covering all 32 banks per instr.

typedef float  f32x4  __attribute__((ext_vector_type(4)));
typedef short  short8 __attribute__((ext_vector_type(8)));
typedef unsigned short ushort4v __attribute__((ext_vector_type(4)));
typedef unsigned short ushort8v __attribute__((ext_vector_type(8)));

__device__ __forceinline__ unsigned short f2bf(float f) {
    unsigned u = __builtin_bit_cast(unsigned, f);
    u += 0x7fffu + ((u >> 16) & 1u);          // RNE (inputs finite)
    return (unsigned short)(u >> 16);
}

__device__ __forceinline__ void ld_lds16(const unsigned short* g, unsigned short* l) {
    __builtin_amdgcn_global_load_lds(
        (const __attribute__((address_space(1))) unsigned int*)g,
        (__attribute__((address_space(3))) unsigned int*)l,
        16, 0, 0);
}

// ---------------- layout constants (ushort units) ----------------
#define XP_U 288                 // per u' row: 36 v' * 8 c
#define XP_G 9792                // per (n,g): 34 * XP_U
#define XP_N 313344              // per n: 32 g * XP_G
#define WP_G 8192                // per (pi,g): 2 pj * 4 sub * 128 o * 8 c
#define WP_PI 262144             // 32 g * WP_G
#define WROW 1040                // LDS sh-stride per (pj,sub) row
#define WBUFS 8320               // 8 * WROW per buffer

// Wp2[pi][g][pj][sub][o][c8] = bf16(W[o][g*8+c8][pi+2du][pj+2dv]), sub=2du+dv
__global__ __launch_bounds__(256) void prepack_w2(const float* __restrict__ W,
                                                  unsigned short* __restrict__ wp) {
    int t = blockIdx.x * 256 + threadIdx.x;   // (o,c) in [0, 32768)
    int o = t >> 8, c = t & 255;
    int g = c >> 3, c8 = c & 7;
    const float4* src = (const float4*)(W + (size_t)(o * 256 + c) * 16);
    float4 q0 = src[0], q1 = src[1], q2 = src[2], q3 = src[3];
    float rows[4][4] = {{q0.x,q0.y,q0.z,q0.w},{q1.x,q1.y,q1.z,q1.w},
                        {q2.x,q2.y,q2.z,q2.w},{q3.x,q3.y,q3.z,q3.w}};
    #pragma unroll
    for (int pi = 0; pi < 2; ++pi)
    #pragma unroll
    for (int pj = 0; pj < 2; ++pj)
    #pragma unroll
    for (int du = 0; du < 2; ++du)
    #pragma unroll
    for (int dv = 0; dv < 2; ++dv)
        wp[pi*WP_PI + g*WP_G + pj*4096 + (du*2+dv)*1024 + o*8 + c8] =
            f2bf(rows[pi+2*du][pj+2*dv]);
}

// xp[n][g][u'][v'][c8] = bf16(x[n][g*8+c8][u'-1][v'-1]); u'/v' out of range -> 0.
__global__ __launch_bounds__(256) void prepack_x(const float* __restrict__ x,
                                                 unsigned short* __restrict__ xp) {
    __shared__ unsigned short xt[256 * 32];   // [c][v] bf16, 16 KB
    const int tid = threadIdx.x;
    const int up  = blockIdx.x;               // u' in [0,34)
    const int n   = blockIdx.y;
    const bool interior = (up >= 1 && up <= 32);

    if (interior) {
        const int u = up - 1;
        #pragma unroll
        for (int k = 0; k < 8; ++k) {
            int idx4 = tid + k * 256;          // [0,2048) float4 units
            int c = idx4 >> 3, v4 = idx4 & 7;
            float4 val = *(const float4*)(x + ((size_t)(n*256 + c)*32 + u)*32 + v4*4);
            ushort4v s = { f2bf(val.x), f2bf(val.y), f2bf(val.z), f2bf(val.w) };
            *(ushort4v*)&xt[c*32 + v4*4] = s;
        }
        __syncthreads();
    }

    #pragma unroll
    for (int s = 0; s < 5; ++s) {
        int id = tid + s * 256;                // (g, v') in [0, 32*36)
        if (id < 1152) {
            int g = id / 36, vp = id % 36;
            ushort8v o8 = {0,0,0,0,0,0,0,0};
            if (interior && vp >= 1 && vp <= 32) {      // v = vp-1 in [0,32)
                #pragma unroll
                for (int e = 0; e < 8; ++e)
                    o8[e] = xt[(g*8 + e)*32 + (vp - 1)];
            }
            *(ushort8v*)&xp[(size_t)n*XP_N + g*XP_G + up*XP_U + vp*8] = o8;
        }
    }
}

// Main: grid 512 = (pi, aq in [0,8), n) XCD-swizzled; 256 thr = 4 waves (pjw, half).
// Block tile: 128 o x (4 arows x 32 b x 2 pj). Wave: 128 o x 64 px -> 8x4 MFMA tiles.
__global__ __launch_bounds__(256, 3) void tconv_main(
    const unsigned short* __restrict__ xp,
    const unsigned short* __restrict__ wp,
    const float* __restrict__ bias,
    float* __restrict__ out)
{
    // W only: 3 buffers x 8320 sh = 24960 sh = 49920 B  -> 3 blocks/CU
    __shared__ __align__(16) unsigned short lds[24960];
    unsigned short* wsh0 = lds;

    const int tid  = threadIdx.x;
    const int lane = tid & 63;
    const int w    = tid >> 6;       // wave 0..3
    const int pjw  = w >> 1;
    const int half = w & 1;
    const int lg   = lane >> 4;      // sub = (du,dv)
    const int ln   = lane & 15;
    const int du   = lg >> 1, dv = lg & 1;

    const int bid = blockIdx.x;
    const int wg  = (bid & 7) * 64 + (bid >> 3);   // XCD swizzle (512 % 8 == 0)
    const int n   = wg >> 4;
    const int aq  = (wg >> 1) & 7;
    const int pi  = wg & 1;
    const int a0  = aq * 4;

    const unsigned short* xpb = xp + (size_t)n * XP_N + (a0 + pi) * XP_U;
    const unsigned short* wpb = wp + pi * WP_PI;

    // per-lane fragment offsets (static after unroll)
    int xoff[4];
    #pragma unroll
    for (int jj = 0; jj < 4; ++jj) {
        int rr = half * 2 + (jj >> 1) + du;
        int vv = (jj & 1) * 16 + ln + pjw + dv;
        xoff[jj] = rr * XP_U + vv * 8;
    }
    const int wfoff = (pjw * 4 + lg) * WROW + ln * 8;

    f32x4 acc[8][4];
    #pragma unroll
    for (int i = 0; i < 8; ++i)
        #pragma unroll
        for (int jj = 0; jj < 4; ++jj)
            acc[i][jj] = (f32x4){0.f, 0.f, 0.f, 0.f};

    short8 xA[4], xB[4];

#define STAGE_W(CH, WBUF)                                                    \
    { const unsigned short* ws_ = wpb + (size_t)(CH) * WP_G;                 \
      unsigned short* wd_ = wsh0 + (WBUF) * WBUFS;                           \
      _Pragma("unroll")                                                      \
      for (int s_ = 0; s_ < 4; ++s_) {                                       \
          int r_ = w * 2 + (s_ >> 1), h_ = s_ & 1;                           \
          ld_lds16(ws_ + r_ * 1024 + h_ * 512 + lane * 8,                    \
                   wd_ + r_ * WROW + h_ * 512); } }

#define LOAD_X(CH, XS)                                                      \
    { const unsigned short* xs_ = xpb + (size_t)(CH) * XP_G;                 \
      _Pragma("unroll")                                                      \
      for (int jj_ = 0; jj_ < 4; ++jj_)                                      \
          XS[jj_] = *(const short8*)(xs_ + xoff[jj_]); }

// Body: wait vmcnt(VMN); barrier; [issue W(CH+2)->SBUF]; MFMA from BUF;
// [issue x(CH+2) into XS after consumption]
#define CHUNK(BUF, SBUF, XS, CH, VMN, DO_W, DO_X)                            \
    {                                                                        \
        __builtin_amdgcn_sched_barrier(0);                                   \
        asm volatile("s_waitcnt vmcnt(" #VMN ")" ::: "memory");              \
        __builtin_amdgcn_s_barrier();                                        \
        __builtin_amdgcn_sched_barrier(0);                                   \
        if (DO_W) STAGE_W((CH) + 2, SBUF);                                   \
        const unsigned short* wb_ = wsh0 + (BUF) * WBUFS + wfoff;            \
        __builtin_amdgcn_s_setprio(1);                                       \
        _Pragma("unroll")                                                    \
        for (int i_ = 0; i_ < 8; ++i_) {                                     \
            short8 av_ = *(const short8*)&wb_[i_ * 128];                     \
            _Pragma("unroll")                                                \
            for (int jj_ = 0; jj_ < 4; ++jj_)                                \
                acc[i_][jj_] = __builtin_amdgcn_mfma_f32_16x16x32_bf16(      \
                    av_, XS[jj_], acc[i_][jj_], 0, 0, 0);                    \
        }                                                                    \
        __builtin_amdgcn_s_setprio(0);                                       \
        if (DO_X) LOAD_X((CH) + 2, XS);                                      \
    }

    // Prologue ledger: [W0, x0, W1, x1] -> first wait vmcnt(8) retires W0,x0.
    STAGE_W(0, 0);
    __builtin_amdgcn_sched_barrier(0);
    LOAD_X(0, xA);
    __builtin_amdgcn_sched_barrier(0);
    STAGE_W(1, 1);
    __builtin_amdgcn_sched_barrier(0);
    LOAD_X(1, xB);
    __builtin_amdgcn_sched_barrier(0);

    // Steady state: chunk ch consumes buf[ch%3], stages W(ch+2)->buf[(ch+2)%3]
    // (== buf[(ch-1)%3], freed: all waves' ch-1 LDS reads completed into regs
    // before they passed barrier(ch)). x ping-pong distance 2.
    for (int c6 = 0; c6 < 30; c6 += 6) {
        CHUNK(0, 2, xA, c6 + 0, 8, 1, 1);
        CHUNK(1, 0, xB, c6 + 1, 8, 1, 1);
        CHUNK(2, 1, xA, c6 + 2, 8, 1, 1);
        CHUNK(0, 2, xB, c6 + 3, 8, 1, 1);
        CHUNK(1, 0, xA, c6 + 4, 8, 1, 1);
        CHUNK(2, 1, xB, c6 + 5, 8, 1, 1);
    }
    // Tail: queue at ch=30 is [W30,x30,W31,x31] -> vmcnt(8); at 31 -> vmcnt(4).
    CHUNK(0, 2, xA, 30, 8, 0, 0);
    CHUNK(1, 0, xB, 31, 4, 0, 0);

#undef CHUNK
#undef LOAD_X
#undef STAGE_W

    // Epilogue: LDS transpose -> coalesced float4 stores.
    // epi rows: row_w = (r*4+lg)*8 + ar*2 + pjw  (o_l' = r*4+lg).
    // lg-quarters of one store differ by 8 rows -> bank starts 0/8/16/24:
    // conflict-free. Reads: float2 pairs cover all 32 banks per instr.
    float* epi = (float*)lds;
    #pragma unroll
    for (int i = 0; i < 8; ++i) {
        __syncthreads();
        f32x4 bv = *(const f32x4*)&bias[i * 16 + lg * 4];
        #pragma unroll
        for (int jj = 0; jj < 4; ++jj) {
            int ar = half * 2 + (jj >> 1);
            int b  = (jj & 1) * 16 + ln;
            #pragma unroll
            for (int r = 0; r < 4; ++r)
                epi[((r * 4 + lg) * 8 + ar * 2 + pjw) * 33 + b] = acc[i][jj][r] + bv[r];
        }
        __syncthreads();
        #pragma unroll
        for (int k = 0; k < 4; ++k) {
            int f    = tid + k * 256;    // [0,1024) float4-store ids
            int row  = f >> 4;           // o_l'(row>>2) x ar(row&3)
            int q    = f & 15;
            float2 A = *(const float2*)&epi[(row * 2 + 0) * 33 + q * 2];
            float2 B = *(const float2*)&epi[(row * 2 + 1) * 33 + q * 2];
            float4 v = { A.x, B.x, A.y, B.y };
            int olp   = row >> 2;        // o_l' = r*4 + lg
            int o     = i * 16 + ((olp & 3) << 2) + (olp >> 2);   // o_l = lg*4+r
            int i_out = 2 * (a0 + (row & 3)) + pi;
            *(float4*)&out[(((size_t)n * 128 + o) * 64 + i_out) * 64 + q * 4] = v;
        }
    }
}

// =================== fallback: round-2 kernel (proven) ===================
__global__ __launch_bounds__(256) void prepack_w(const float* __restrict__ W,
                                                 unsigned short* __restrict__ Wp) {
    int t = blockIdx.x * 256 + threadIdx.x;
    int o = t >> 8, c = t & 255;
    const float4* src = (const float4*)(W + (size_t)(o * 256 + c) * 16);
    float4 q0 = src[0], q1 = src[1], q2 = src[2], q3 = src[3];
    float rows[4][4] = {{q0.x,q0.y,q0.z,q0.w},{q1.x,q1.y,q1.z,q1.w},
                        {q2.x,q2.y,q2.z,q2.w},{q3.x,q3.y,q3.z,q3.w}};
    #pragma unroll
    for (int pi = 0; pi < 2; ++pi)
    #pragma unroll
    for (int pj = 0; pj < 2; ++pj)
    #pragma unroll
    for (int du = 0; du < 2; ++du)
    #pragma unroll
    for (int dv = 0; dv < 2; ++dv)
        Wp[((((pi*2+pj)*4 + du*2+dv)*128 + o)*256) + c] = f2bf(rows[pi+2*du][pj+2*dv]);
}

template<bool PRE>
__global__ __launch_bounds__(512, 2) void tconv_mfma(
    const float* __restrict__ x, const float* __restrict__ W,
    const unsigned short* __restrict__ Wp, const float* __restrict__ bias,
    float* __restrict__ out)
{
    __shared__ __align__(16) unsigned short xsh[2][9 * 34 * 8];
    __shared__ __align__(16) unsigned short wsh[2][2 * 4 * 128 * 8];

    const int tid = threadIdx.x;
    const int bid = blockIdx.x;
    const int pi  = bid & 1;
    const int aq  = (bid >> 1) & 3;
    const int n   = bid >> 3;
    const int a0  = aq * 8;
    const int u0  = a0 + pi - 1;

    const int l   = tid & 63;
    const int w   = tid >> 6;
    const int pjw = w >> 2;
    const int q   = w & 3;
    const int lg  = l >> 4;
    const int ln  = l & 15;

    const int sv = tid & 31;
    const int sg = tid >> 5;

    f32x4 acc[8][4];
    #pragma unroll
    for (int i = 0; i < 8; ++i)
        #pragma unroll
        for (int jj = 0; jj < 4; ++jj)
            acc[i][jj] = (f32x4){0.f, 0.f, 0.f, 0.f};

    float    xv[5];
    ushort4v wv[4];
    float4   wa[2], wb[2];

    auto stage_load = [&](int ch) {
        const int c0 = ch * 8;
        #pragma unroll
        for (int s = 0; s < 5; ++s) {
            int p = sg * 5 + s;
            if (p < 72) {
                int c = p & 7, rr = p >> 3;
                int u = u0 + rr;
                xv[s] = ((unsigned)u < 32u)
                      ? x[((n*256 + c0 + c)*32 + u)*32 + sv] : 0.f;
            }
        }
        if (PRE) {
            #pragma unroll
            for (int k = 0; k < 4; ++k) {
                int uu = tid + k * 512;
                int chalf = uu & 1, o = (uu >> 1) & 127;
                int sub = (uu >> 8) & 3, pjq = (uu >> 10) & 1;
                wv[k] = *(const ushort4v*)&Wp[(((pi*2 + pjq)*4 + sub)*128 + o)*256
                                              + c0 + chalf*4];
            }
        } else {
            #pragma unroll
            for (int k = 0; k < 2; ++k) {
                int pr = tid + k * 512;
                int o = pr >> 3, c = pr & 7;
                const float* base = W + ((o*256 + c0 + c) << 4) + pi*4;
                wa[k] = *(const float4*)base;
                wb[k] = *(const float4*)(base + 8);
            }
        }
    };

    auto stage_write = [&](int buf) {
        #pragma unroll
        for (int s = 0; s < 5; ++s) {
            int p = sg * 5 + s;
            if (p < 72) {
                int c = p & 7, rr = p >> 3;
                xsh[buf][(rr*34 + sv + 1)*8 + c] = f2bf(xv[s]);
            }
        }
        if (tid < 144) {
            int pr = tid >> 1;
            int rr = pr >> 3, c = pr & 7;
            int cw = (tid & 1) * 33;
            xsh[buf][(rr*34 + cw)*8 + c] = 0;
        }
        if (PRE) {
            #pragma unroll
            for (int k = 0; k < 4; ++k) {
                int uu = tid + k * 512;
                int chalf = uu & 1, o = (uu >> 1) & 127;
                int sub = (uu >> 8) & 3, pjq = (uu >> 10) & 1;
                *(ushort4v*)&wsh[buf][(((pjq*4 + sub)*128 + o)*8) + chalf*4] = wv[k];
            }
        } else {
            #pragma unroll
            for (int k = 0; k < 2; ++k) {
                int pr = tid + k * 512;
                int o = pr >> 3, c = pr & 7;
                float ra[4] = {wa[k].x, wa[k].y, wa[k].z, wa[k].w};
                float rb[4] = {wb[k].x, wb[k].y, wb[k].z, wb[k].w};
                #pragma unroll
                for (int pj2 = 0; pj2 < 2; ++pj2)
                #pragma unroll
                for (int duu = 0; duu < 2; ++duu)
                #pragma unroll
                for (int dvv = 0; dvv < 2; ++dvv) {
                    float val = duu ? rb[pj2 + 2*dvv] : ra[pj2 + 2*dvv];
                    wsh[buf][(((pj2*4 + duu*2 + dvv)*128 + o)*8) + c] = f2bf(val);
                }
            }
        }
    };

    stage_load(0);
    stage_write(0);
    __syncthreads();

    for (int ch = 0; ch < 32; ++ch) {
        const int cur = ch & 1;
        if (ch + 1 < 32) stage_load(ch + 1);

        short8 bfr[4];
        #pragma unroll
        for (int jj = 0; jj < 4; ++jj) {
            int arow = q*2 + (jj >> 1);
            int b    = (jj & 1)*16 + ln;
            int rr   = arow + (lg >> 1);
            int cw   = b + pjw + (lg & 1);
            bfr[jj]  = *(const short8*)&xsh[cur][(rr*34 + cw)*8];
        }
        #pragma unroll
        for (int i = 0; i < 8; ++i) {
            short8 av = *(const short8*)&wsh[cur][((pjw*4 + lg)*128 + i*16 + ln)*8];
            #pragma unroll
            for (int jj = 0; jj < 4; ++jj)
                acc[i][jj] = __builtin_amdgcn_mfma_f32_16x16x32_bf16(
                                 av, bfr[jj], acc[i][jj], 0, 0, 0);
        }

        if (ch + 1 < 32) stage_write(cur ^ 1);
        __syncthreads();
    }

    #pragma unroll
    for (int i = 0; i < 8; ++i) {
        const f32x4 bv = *(const f32x4*)&bias[i*16 + lg*4];
        #pragma unroll
        for (int jj = 0; jj < 4; ++jj) {
            int arow  = q*2 + (jj >> 1);
            int b     = (jj & 1)*16 + ln;
            int i_out = 2*(a0 + arow) + pi;
            int j_out = 2*b + pjw;
            int o0    = i*16 + lg*4;
            int base  = ((n*128 + o0)*64 + i_out)*64 + j_out;
            #pragma unroll
            for (int r = 0; r < 4; ++r)
                out[base + r*4096] = acc[i][jj][r] + bv[r];
        }
    }
}

extern "C" void kernel_launch(void* const* d_in, const int* in_sizes, int n_in,
                              void* d_out, int out_size, void* d_ws, size_t ws_size,
                              hipStream_t stream) {
    const float* x    = (const float*)d_in[0];
    const float* W    = (const float*)d_in[1];
    const float* bias = (const float*)d_in[2];
    float* out        = (float*)d_out;

    const size_t wp2_bytes = (size_t)2 * WP_PI * 2;          // 1 MB
    const size_t xp_bytes  = (size_t)32 * XP_N * 2;          // ~20 MB
    if (ws_size >= wp2_bytes + xp_bytes) {
        unsigned short* wp2 = (unsigned short*)d_ws;
        unsigned short* xpp = (unsigned short*)((char*)d_ws + wp2_bytes);
        prepack_w2<<<128, 256, 0, stream>>>(W, wp2);
        prepack_x<<<dim3(34, 32), 256, 0, stream>>>(x, xpp);
        tconv_main<<<512, 256, 0, stream>>>(xpp, wp2, bias, out);
    } else if (ws_size >= (size_t)4*4*128*256*2) {
        unsigned short* Wp = (unsigned short*)d_ws;
        prepack_w<<<128, 256, 0, stream>>>(W, Wp);
        tconv_mfma<true><<<256, 512, 0, stream>>>(x, W, Wp, bias, out);
    } else {
        tconv_mfma<false><<<256, 512, 0, stream>>>(x, W, nullptr, bias, out);
    }
}

// Round 9
// 186.738 us; speedup vs baseline: 1.0029x; 1.0014x over previous
//
#include <hip/hip_runtime.h>

// Transposed conv (stride 2, 4x4, pad 2) as bf16 MFMA implicit GEMM, v6.
// x: (32,256,32,32) f32, W: (128,256,4,4) OIHW f32, b: (128,), out: (32,128,64,64) f32
// y[n,o,2a+pi,2b+pj] = bias[o] + sum_{c,du,dv} W[o,c,pi+2du,pj+2dv] * x[n,c,a+pi-1+du,b+pj-1+dv]
//
// v6 vs v5: (1) 3-buffer W LDS (50 KB) -> 3 blocks/CU (3 waves/SIMD, +50% TLP),
// distance-2 prefetch, steady vmcnt(8); (2) s_setprio around MFMA cluster (T5 —
// co-resident blocks now at different phases); (3) epilogue bank-conflict fix:
// write rows remapped so lg-quarters hit bank offsets 0/8/16/24, reads as
// float2 pairs covering all 32 banks per instr.

typedef float  f32x4  __attribute__((ext_vector_type(4)));
typedef short  short8 __attribute__((ext_vector_type(8)));
typedef unsigned short ushort4v __attribute__((ext_vector_type(4)));
typedef unsigned short ushort8v __attribute__((ext_vector_type(8)));

__device__ __forceinline__ unsigned short f2bf(float f) {
    unsigned u = __builtin_bit_cast(unsigned, f);
    u += 0x7fffu + ((u >> 16) & 1u);          // RNE (inputs finite)
    return (unsigned short)(u >> 16);
}

__device__ __forceinline__ void ld_lds16(const unsigned short* g, unsigned short* l) {
    __builtin_amdgcn_global_load_lds(
        (const __attribute__((address_space(1))) unsigned int*)g,
        (__attribute__((address_space(3))) unsigned int*)l,
        16, 0, 0);
}

// ---------------- layout constants (ushort units) ----------------
#define XP_U 288                 // per u' row: 36 v' * 8 c
#define XP_G 9792                // per (n,g): 34 * XP_U
#define XP_N 313344              // per n: 32 g * XP_G
#define WP_G 8192                // per (pi,g): 2 pj * 4 sub * 128 o * 8 c
#define WP_PI 262144             // 32 g * WP_G
#define WROW 1040                // LDS sh-stride per (pj,sub) row
#define WBUFS 8320               // 8 * WROW per buffer

// Wp2[pi][g][pj][sub][o][c8] = bf16(W[o][g*8+c8][pi+2du][pj+2dv]), sub=2du+dv
__global__ __launch_bounds__(256) void prepack_w2(const float* __restrict__ W,
                                                  unsigned short* __restrict__ wp) {
    int t = blockIdx.x * 256 + threadIdx.x;   // (o,c) in [0, 32768)
    int o = t >> 8, c = t & 255;
    int g = c >> 3, c8 = c & 7;
    const float4* src = (const float4*)(W + (size_t)(o * 256 + c) * 16);
    float4 q0 = src[0], q1 = src[1], q2 = src[2], q3 = src[3];
    float rows[4][4] = {{q0.x,q0.y,q0.z,q0.w},{q1.x,q1.y,q1.z,q1.w},
                        {q2.x,q2.y,q2.z,q2.w},{q3.x,q3.y,q3.z,q3.w}};
    #pragma unroll
    for (int pi = 0; pi < 2; ++pi)
    #pragma unroll
    for (int pj = 0; pj < 2; ++pj)
    #pragma unroll
    for (int du = 0; du < 2; ++du)
    #pragma unroll
    for (int dv = 0; dv < 2; ++dv)
        wp[pi*WP_PI + g*WP_G + pj*4096 + (du*2+dv)*1024 + o*8 + c8] =
            f2bf(rows[pi+2*du][pj+2*dv]);
}

// xp[n][g][u'][v'][c8] = bf16(x[n][g*8+c8][u'-1][v'-1]); u'/v' out of range -> 0.
__global__ __launch_bounds__(256) void prepack_x(const float* __restrict__ x,
                                                 unsigned short* __restrict__ xp) {
    __shared__ unsigned short xt[256 * 32];   // [c][v] bf16, 16 KB
    const int tid = threadIdx.x;
    const int up  = blockIdx.x;               // u' in [0,34)
    const int n   = blockIdx.y;
    const bool interior = (up >= 1 && up <= 32);

    if (interior) {
        const int u = up - 1;
        #pragma unroll
        for (int k = 0; k < 8; ++k) {
            int idx4 = tid + k * 256;          // [0,2048) float4 units
            int c = idx4 >> 3, v4 = idx4 & 7;
            float4 val = *(const float4*)(x + ((size_t)(n*256 + c)*32 + u)*32 + v4*4);
            ushort4v s = { f2bf(val.x), f2bf(val.y), f2bf(val.z), f2bf(val.w) };
            *(ushort4v*)&xt[c*32 + v4*4] = s;
        }
        __syncthreads();
    }

    #pragma unroll
    for (int s = 0; s < 5; ++s) {
        int id = tid + s * 256;                // (g, v') in [0, 32*36)
        if (id < 1152) {
            int g = id / 36, vp = id % 36;
            ushort8v o8 = {0,0,0,0,0,0,0,0};
            if (interior && vp >= 1 && vp <= 32) {      // v = vp-1 in [0,32)
                #pragma unroll
                for (int e = 0; e < 8; ++e)
                    o8[e] = xt[(g*8 + e)*32 + (vp - 1)];
            }
            *(ushort8v*)&xp[(size_t)n*XP_N + g*XP_G + up*XP_U + vp*8] = o8;
        }
    }
}

// Main: grid 512 = (pi, aq in [0,8), n) XCD-swizzled; 256 thr = 4 waves (pjw, half).
// Block tile: 128 o x (4 arows x 32 b x 2 pj). Wave: 128 o x 64 px -> 8x4 MFMA tiles.
__global__ __launch_bounds__(256, 3) void tconv_main(
    const unsigned short* __restrict__ xp,
    const unsigned short* __restrict__ wp,
    const float* __restrict__ bias,
    float* __restrict__ out)
{
    // W only: 3 buffers x 8320 sh = 24960 sh = 49920 B  -> 3 blocks/CU
    __shared__ __align__(16) unsigned short lds[24960];
    unsigned short* wsh0 = lds;

    const int tid  = threadIdx.x;
    const int lane = tid & 63;
    const int w    = tid >> 6;       // wave 0..3
    const int pjw  = w >> 1;
    const int half = w & 1;
    const int lg   = lane >> 4;      // sub = (du,dv)
    const int ln   = lane & 15;
    const int du   = lg >> 1, dv = lg & 1;

    const int bid = blockIdx.x;
    const int wg  = (bid & 7) * 64 + (bid >> 3);   // XCD swizzle (512 % 8 == 0)
    const int n   = wg >> 4;
    const int aq  = (wg >> 1) & 7;
    const int pi  = wg & 1;
    const int a0  = aq * 4;

    const unsigned short* xpb = xp + (size_t)n * XP_N + (a0 + pi) * XP_U;
    const unsigned short* wpb = wp + pi * WP_PI;

    // per-lane fragment offsets (static after unroll)
    int xoff[4];
    #pragma unroll
    for (int jj = 0; jj < 4; ++jj) {
        int rr = half * 2 + (jj >> 1) + du;
        int vv = (jj & 1) * 16 + ln + pjw + dv;
        xoff[jj] = rr * XP_U + vv * 8;
    }
    const int wfoff = (pjw * 4 + lg) * WROW + ln * 8;

    f32x4 acc[8][4];
    #pragma unroll
    for (int i = 0; i < 8; ++i)
        #pragma unroll
        for (int jj = 0; jj < 4; ++jj)
            acc[i][jj] = (f32x4){0.f, 0.f, 0.f, 0.f};

    short8 xA[4], xB[4];

#define STAGE_W(CH, WBUF)                                                    \
    { const unsigned short* ws_ = wpb + (size_t)(CH) * WP_G;                 \
      unsigned short* wd_ = wsh0 + (WBUF) * WBUFS;                           \
      _Pragma("unroll")                                                      \
      for (int s_ = 0; s_ < 4; ++s_) {                                       \
          int r_ = w * 2 + (s_ >> 1), h_ = s_ & 1;                           \
          ld_lds16(ws_ + r_ * 1024 + h_ * 512 + lane * 8,                    \
                   wd_ + r_ * WROW + h_ * 512); } }

#define LOAD_X(CH, XS)                                                      \
    { const unsigned short* xs_ = xpb + (size_t)(CH) * XP_G;                 \
      _Pragma("unroll")                                                      \
      for (int jj_ = 0; jj_ < 4; ++jj_)                                      \
          XS[jj_] = *(const short8*)(xs_ + xoff[jj_]); }

// Body: wait vmcnt(VMN); barrier; [issue W(CH+2)->SBUF]; MFMA from BUF;
// [issue x(CH+2) into XS after consumption]
#define CHUNK(BUF, SBUF, XS, CH, VMN, DO_W, DO_X)                            \
    {                                                                        \
        __builtin_amdgcn_sched_barrier(0);                                   \
        asm volatile("s_waitcnt vmcnt(" #VMN ")" ::: "memory");              \
        __builtin_amdgcn_s_barrier();                                        \
        __builtin_amdgcn_sched_barrier(0);                                   \
        if (DO_W) STAGE_W((CH) + 2, SBUF);                                   \
        const unsigned short* wb_ = wsh0 + (BUF) * WBUFS + wfoff;            \
        __builtin_amdgcn_s_setprio(1);                                       \
        _Pragma("unroll")                                                    \
        for (int i_ = 0; i_ < 8; ++i_) {                                     \
            short8 av_ = *(const short8*)&wb_[i_ * 128];                     \
            _Pragma("unroll")                                                \
            for (int jj_ = 0; jj_ < 4; ++jj_)                                \
                acc[i_][jj_] = __builtin_amdgcn_mfma_f32_16x16x32_bf16(      \
                    av_, XS[jj_], acc[i_][jj_], 0, 0, 0);                    \
        }                                                                    \
        __builtin_amdgcn_s_setprio(0);                                       \
        if (DO_X) LOAD_X((CH) + 2, XS);                                      \
    }

    // Prologue ledger: [W0, x0, W1, x1] -> first wait vmcnt(8) retires W0,x0.
    STAGE_W(0, 0);
    __builtin_amdgcn_sched_barrier(0);
    LOAD_X(0, xA);
    __builtin_amdgcn_sched_barrier(0);
    STAGE_W(1, 1);
    __builtin_amdgcn_sched_barrier(0);
    LOAD_X(1, xB);
    __builtin_amdgcn_sched_barrier(0);

    // Steady state: chunk ch consumes buf[ch%3], stages W(ch+2)->buf[(ch+2)%3]
    // (== buf[(ch-1)%3], freed: all waves' ch-1 LDS reads completed into regs
    // before they passed barrier(ch)). x ping-pong distance 2.
    for (int c6 = 0; c6 < 30; c6 += 6) {
        CHUNK(0, 2, xA, c6 + 0, 8, 1, 1);
        CHUNK(1, 0, xB, c6 + 1, 8, 1, 1);
        CHUNK(2, 1, xA, c6 + 2, 8, 1, 1);
        CHUNK(0, 2, xB, c6 + 3, 8, 1, 1);
        CHUNK(1, 0, xA, c6 + 4, 8, 1, 1);
        CHUNK(2, 1, xB, c6 + 5, 8, 1, 1);
    }
    // Tail: queue at ch=30 is [W30,x30,W31,x31] -> vmcnt(8); at 31 -> vmcnt(4).
    CHUNK(0, 2, xA, 30, 8, 0, 0);
    CHUNK(1, 0, xB, 31, 4, 0, 0);

#undef CHUNK
#undef LOAD_X
#undef STAGE_W

    // Epilogue: LDS transpose -> coalesced float4 stores.
    // epi rows: row_w = (r*4+lg)*8 + ar*2 + pjw  (o_l' = r*4+lg).
    // lg-quarters of one store differ by 8 rows -> bank starts 0/8/16/24:
    // conflict-free. Reads: float2 pairs cover all 32 banks per instr.
    float* epi = (float*)lds;
    #pragma unroll
    for (int i = 0; i < 8; ++i) {
        __syncthreads();
        f32x4 bv = *(const f32x4*)&bias[i * 16 + lg * 4];
        #pragma unroll
        for (int jj = 0; jj < 4; ++jj) {
            int ar = half * 2 + (jj >> 1);
            int b  = (jj & 1) * 16 + ln;
            #pragma unroll
            for (int r = 0; r < 4; ++r)
                epi[((r * 4 + lg) * 8 + ar * 2 + pjw) * 33 + b] = acc[i][jj][r] + bv[r];
        }
        __syncthreads();
        #pragma unroll
        for (int k = 0; k < 4; ++k) {
            int f    = tid + k * 256;    // [0,1024) float4-store ids
            int row  = f >> 4;           // o_l'(row>>2) x ar(row&3)
            int q    = f & 15;
            float2 A = *(const float2*)&epi[(row * 2 + 0) * 33 + q * 2];
            float2 B = *(const float2*)&epi[(row * 2 + 1) * 33 + q * 2];
            float4 v = { A.x, B.x, A.y, B.y };
            int olp   = row >> 2;        // o_l' = r*4 + lg
            int o     = i * 16 + ((olp & 3) << 2) + (olp >> 2);   // o_l = lg*4+r
            int i_out = 2 * (a0 + (row & 3)) + pi;
            *(float4*)&out[(((size_t)n * 128 + o) * 64 + i_out) * 64 + q * 4] = v;
        }
    }
}

// =================== fallback: round-2 kernel (proven) ===================
__global__ __launch_bounds__(256) void prepack_w(const float* __restrict__ W,
                                                 unsigned short* __restrict__ Wp) {
    int t = blockIdx.x * 256 + threadIdx.x;
    int o = t >> 8, c = t & 255;
    const float4* src = (const float4*)(W + (size_t)(o * 256 + c) * 16);
    float4 q0 = src[0], q1 = src[1], q2 = src[2], q3 = src[3];
    float rows[4][4] = {{q0.x,q0.y,q0.z,q0.w},{q1.x,q1.y,q1.z,q1.w},
                        {q2.x,q2.y,q2.z,q2.w},{q3.x,q3.y,q3.z,q3.w}};
    #pragma unroll
    for (int pi = 0; pi < 2; ++pi)
    #pragma unroll
    for (int pj = 0; pj < 2; ++pj)
    #pragma unroll
    for (int du = 0; du < 2; ++du)
    #pragma unroll
    for (int dv = 0; dv < 2; ++dv)
        Wp[((((pi*2+pj)*4 + du*2+dv)*128 + o)*256) + c] = f2bf(rows[pi+2*du][pj+2*dv]);
}

template<bool PRE>
__global__ __launch_bounds__(512, 2) void tconv_mfma(
    const float* __restrict__ x, const float* __restrict__ W,
    const unsigned short* __restrict__ Wp, const float* __restrict__ bias,
    float* __restrict__ out)
{
    __shared__ __align__(16) unsigned short xsh[2][9 * 34 * 8];
    __shared__ __align__(16) unsigned short wsh[2][2 * 4 * 128 * 8];

    const int tid = threadIdx.x;
    const int bid = blockIdx.x;
    const int pi  = bid & 1;
    const int aq  = (bid >> 1) & 3;
    const int n   = bid >> 3;
    const int a0  = aq * 8;
    const int u0  = a0 + pi - 1;

    const int l   = tid & 63;
    const int w   = tid >> 6;
    const int pjw = w >> 2;
    const int q   = w & 3;
    const int lg  = l >> 4;
    const int ln  = l & 15;

    const int sv = tid & 31;
    const int sg = tid >> 5;

    f32x4 acc[8][4];
    #pragma unroll
    for (int i = 0; i < 8; ++i)
        #pragma unroll
        for (int jj = 0; jj < 4; ++jj)
            acc[i][jj] = (f32x4){0.f, 0.f, 0.f, 0.f};

    float    xv[5];
    ushort4v wv[4];
    float4   wa[2], wb[2];

    auto stage_load = [&](int ch) {
        const int c0 = ch * 8;
        #pragma unroll
        for (int s = 0; s < 5; ++s) {
            int p = sg * 5 + s;
            if (p < 72) {
                int c = p & 7, rr = p >> 3;
                int u = u0 + rr;
                xv[s] = ((unsigned)u < 32u)
                      ? x[((n*256 + c0 + c)*32 + u)*32 + sv] : 0.f;
            }
        }
        if (PRE) {
            #pragma unroll
            for (int k = 0; k < 4; ++k) {
                int uu = tid + k * 512;
                int chalf = uu & 1, o = (uu >> 1) & 127;
                int sub = (uu >> 8) & 3, pjq = (uu >> 10) & 1;
                wv[k] = *(const ushort4v*)&Wp[(((pi*2 + pjq)*4 + sub)*128 + o)*256
                                              + c0 + chalf*4];
            }
        } else {
            #pragma unroll
            for (int k = 0; k < 2; ++k) {
                int pr = tid + k * 512;
                int o = pr >> 3, c = pr & 7;
                const float* base = W + ((o*256 + c0 + c) << 4) + pi*4;
                wa[k] = *(const float4*)base;
                wb[k] = *(const float4*)(base + 8);
            }
        }
    };

    auto stage_write = [&](int buf) {
        #pragma unroll
        for (int s = 0; s < 5; ++s) {
            int p = sg * 5 + s;
            if (p < 72) {
                int c = p & 7, rr = p >> 3;
                xsh[buf][(rr*34 + sv + 1)*8 + c] = f2bf(xv[s]);
            }
        }
        if (tid < 144) {
            int pr = tid >> 1;
            int rr = pr >> 3, c = pr & 7;
            int cw = (tid & 1) * 33;
            xsh[buf][(rr*34 + cw)*8 + c] = 0;
        }
        if (PRE) {
            #pragma unroll
            for (int k = 0; k < 4; ++k) {
                int uu = tid + k * 512;
                int chalf = uu & 1, o = (uu >> 1) & 127;
                int sub = (uu >> 8) & 3, pjq = (uu >> 10) & 1;
                *(ushort4v*)&wsh[buf][(((pjq*4 + sub)*128 + o)*8) + chalf*4] = wv[k];
            }
        } else {
            #pragma unroll
            for (int k = 0; k < 2; ++k) {
                int pr = tid + k * 512;
                int o = pr >> 3, c = pr & 7;
                float ra[4] = {wa[k].x, wa[k].y, wa[k].z, wa[k].w};
                float rb[4] = {wb[k].x, wb[k].y, wb[k].z, wb[k].w};
                #pragma unroll
                for (int pj2 = 0; pj2 < 2; ++pj2)
                #pragma unroll
                for (int duu = 0; duu < 2; ++duu)
                #pragma unroll
                for (int dvv = 0; dvv < 2; ++dvv) {
                    float val = duu ? rb[pj2 + 2*dvv] : ra[pj2 + 2*dvv];
                    wsh[buf][(((pj2*4 + duu*2 + dvv)*128 + o)*8) + c] = f2bf(val);
                }
            }
        }
    };

    stage_load(0);
    stage_write(0);
    __syncthreads();

    for (int ch = 0; ch < 32; ++ch) {
        const int cur = ch & 1;
        if (ch + 1 < 32) stage_load(ch + 1);

        short8 bfr[4];
        #pragma unroll
        for (int jj = 0; jj < 4; ++jj) {
            int arow = q*2 + (jj >> 1);
            int b    = (jj & 1)*16 + ln;
            int rr   = arow + (lg >> 1);
            int cw   = b + pjw + (lg & 1);
            bfr[jj]  = *(const short8*)&xsh[cur][(rr*34 + cw)*8];
        }
        #pragma unroll
        for (int i = 0; i < 8; ++i) {
            short8 av = *(const short8*)&wsh[cur][((pjw*4 + lg)*128 + i*16 + ln)*8];
            #pragma unroll
            for (int jj = 0; jj < 4; ++jj)
                acc[i][jj] = __builtin_amdgcn_mfma_f32_16x16x32_bf16(
                                 av, bfr[jj], acc[i][jj], 0, 0, 0);
        }

        if (ch + 1 < 32) stage_write(cur ^ 1);
        __syncthreads();
    }

    #pragma unroll
    for (int i = 0; i < 8; ++i) {
        const f32x4 bv = *(const f32x4*)&bias[i*16 + lg*4];
        #pragma unroll
        for (int jj = 0; jj < 4; ++jj) {
            int arow  = q*2 + (jj >> 1);
            int b     = (jj & 1)*16 + ln;
            int i_out = 2*(a0 + arow) + pi;
            int j_out = 2*b + pjw;
            int o0    = i*16 + lg*4;
            int base  = ((n*128 + o0)*64 + i_out)*64 + j_out;
            #pragma unroll
            for (int r = 0; r < 4; ++r)
                out[base + r*4096] = acc[i][jj][r] + bv[r];
        }
    }
}

extern "C" void kernel_launch(void* const* d_in, const int* in_sizes, int n_in,
                              void* d_out, int out_size, void* d_ws, size_t ws_size,
                              hipStream_t stream) {
    const float* x    = (const float*)d_in[0];
    const float* W    = (const float*)d_in[1];
    const float* bias = (const float*)d_in[2];
    float* out        = (float*)d_out;

    const size_t wp2_bytes = (size_t)2 * WP_PI * 2;          // 1 MB
    const size_t xp_bytes  = (size_t)32 * XP_N * 2;          // ~20 MB
    if (ws_size >= wp2_bytes + xp_bytes) {
        unsigned short* wp2 = (unsigned short*)d_ws;
        unsigned short* xpp = (unsigned short*)((char*)d_ws + wp2_bytes);
        prepack_w2<<<128, 256, 0, stream>>>(W, wp2);
        prepack_x<<<dim3(34, 32), 256, 0, stream>>>(x, xpp);
        tconv_main<<<512, 256, 0, stream>>>(xpp, wp2, bias, out);
    } else if (ws_size >= (size_t)4*4*128*256*2) {
        unsigned short* Wp = (unsigned short*)d_ws;
        prepack_w<<<128, 256, 0, stream>>>(W, Wp);
        tconv_mfma<true><<<256, 512, 0, stream>>>(x, W, Wp, bias, out);
    } else {
        tconv_mfma<false><<<256, 512, 0, stream>>>(x, W, nullptr, bias, out);
    }
}

// Round 10
// 63.443 us; speedup vs baseline: 2.9519x; 2.9434x over previous
//
#include <hip/hip_runtime.h>

// Transposed conv (stride 2, 4x4, pad 2) as bf16 MFMA implicit GEMM, v7.
// x: (32,256,32,32) f32, W: (128,256,4,4) OIHW f32, b: (128,), out: (32,128,64,64) f32
// y[n,o,2a+pi,2b+pj] = bias[o] + sum_{c,du,dv} W[o,c,pi+2du,pj+2dv] * x[n,c,a+pi-1+du,b+pj-1+dv]
//
// v7 vs v6: v6's (256,3) bound forced an acc spill (575 MB scratch writes).
// Fix: split o across blocks -> wave tile 64o x 64px, acc = 64 regs/thread,
// total ~120 regs -> 4 waves/SIMD with NO allocator squeeze. Grid 1024 =
// (n, aq, pi, oh) = 4 blocks/CU. 3-buffer W LDS (25.3 KB), uniform vmcnt(6)
// ledger (body k issues W(k+2) then x(k+2)). Epilogue keeps v6's conflict-free
// remap. x B-frags stay global->VGPR (v5, proven).

typedef float  f32x4  __attribute__((ext_vector_type(4)));
typedef short  short8 __attribute__((ext_vector_type(8)));
typedef unsigned short ushort4v __attribute__((ext_vector_type(4)));
typedef unsigned short ushort8v __attribute__((ext_vector_type(8)));

__device__ __forceinline__ unsigned short f2bf(float f) {
    unsigned u = __builtin_bit_cast(unsigned, f);
    u += 0x7fffu + ((u >> 16) & 1u);          // RNE (inputs finite)
    return (unsigned short)(u >> 16);
}

__device__ __forceinline__ void ld_lds16(const unsigned short* g, unsigned short* l) {
    __builtin_amdgcn_global_load_lds(
        (const __attribute__((address_space(1))) unsigned int*)g,
        (__attribute__((address_space(3))) unsigned int*)l,
        16, 0, 0);
}

// ---------------- layout constants (ushort units) ----------------
#define XP_U 288                 // per u' row: 36 v' * 8 c
#define XP_G 9792                // per (n,g): 34 * XP_U
#define XP_N 313344              // per n: 32 g * XP_G
#define WP_G 8192                // per (pi,g): 2 pj * 4 sub * 128 o * 8 c
#define WP_PI 262144             // 32 g * WP_G
#define WROW 528                 // LDS sh-stride per (pj,sub) half-row (512+16 pad)
#define WBUFS 4224               // 8 * WROW per buffer

// Wp2[pi][g][pj][sub][o][c8] = bf16(W[o][g*8+c8][pi+2du][pj+2dv]), sub=2du+dv
__global__ __launch_bounds__(256) void prepack_w2(const float* __restrict__ W,
                                                  unsigned short* __restrict__ wp) {
    int t = blockIdx.x * 256 + threadIdx.x;   // (o,c) in [0, 32768)
    int o = t >> 8, c = t & 255;
    int g = c >> 3, c8 = c & 7;
    const float4* src = (const float4*)(W + (size_t)(o * 256 + c) * 16);
    float4 q0 = src[0], q1 = src[1], q2 = src[2], q3 = src[3];
    float rows[4][4] = {{q0.x,q0.y,q0.z,q0.w},{q1.x,q1.y,q1.z,q1.w},
                        {q2.x,q2.y,q2.z,q2.w},{q3.x,q3.y,q3.z,q3.w}};
    #pragma unroll
    for (int pi = 0; pi < 2; ++pi)
    #pragma unroll
    for (int pj = 0; pj < 2; ++pj)
    #pragma unroll
    for (int du = 0; du < 2; ++du)
    #pragma unroll
    for (int dv = 0; dv < 2; ++dv)
        wp[pi*WP_PI + g*WP_G + pj*4096 + (du*2+dv)*1024 + o*8 + c8] =
            f2bf(rows[pi+2*du][pj+2*dv]);
}

// xp[n][g][u'][v'][c8] = bf16(x[n][g*8+c8][u'-1][v'-1]); u'/v' out of range -> 0.
__global__ __launch_bounds__(256) void prepack_x(const float* __restrict__ x,
                                                 unsigned short* __restrict__ xp) {
    __shared__ unsigned short xt[256 * 32];   // [c][v] bf16, 16 KB
    const int tid = threadIdx.x;
    const int up  = blockIdx.x;               // u' in [0,34)
    const int n   = blockIdx.y;
    const bool interior = (up >= 1 && up <= 32);

    if (interior) {
        const int u = up - 1;
        #pragma unroll
        for (int k = 0; k < 8; ++k) {
            int idx4 = tid + k * 256;          // [0,2048) float4 units
            int c = idx4 >> 3, v4 = idx4 & 7;
            float4 val = *(const float4*)(x + ((size_t)(n*256 + c)*32 + u)*32 + v4*4);
            ushort4v s = { f2bf(val.x), f2bf(val.y), f2bf(val.z), f2bf(val.w) };
            *(ushort4v*)&xt[c*32 + v4*4] = s;
        }
        __syncthreads();
    }

    #pragma unroll
    for (int s = 0; s < 5; ++s) {
        int id = tid + s * 256;                // (g, v') in [0, 32*36)
        if (id < 1152) {
            int g = id / 36, vp = id % 36;
            ushort8v o8 = {0,0,0,0,0,0,0,0};
            if (interior && vp >= 1 && vp <= 32) {      // v = vp-1 in [0,32)
                #pragma unroll
                for (int e = 0; e < 8; ++e)
                    o8[e] = xt[(g*8 + e)*32 + (vp - 1)];
            }
            *(ushort8v*)&xp[(size_t)n*XP_N + g*XP_G + up*XP_U + vp*8] = o8;
        }
    }
}

// Main: grid 1024 = (n, aq in [0,8), pi, oh), XCD-swizzled. 256 thr = 4 waves
// (pjw, half). Block tile: 64 o x (4 arows x 32 b x 2 pj). Wave: 64o x 64px.
__global__ __launch_bounds__(256, 3) void tconv_main(
    const unsigned short* __restrict__ xp,
    const unsigned short* __restrict__ wp,
    const float* __restrict__ bias,
    float* __restrict__ out)
{
    // W only: 3 buffers x 4224 sh = 12672 sh = 25344 B; epi (16.9 KB) overlays.
    __shared__ __align__(16) unsigned short lds[12672];
    unsigned short* wsh0 = lds;

    const int tid  = threadIdx.x;
    const int lane = tid & 63;
    const int w    = tid >> 6;       // wave 0..3
    const int pjw  = w >> 1;
    const int half = w & 1;
    const int lg   = lane >> 4;      // sub = (du,dv)
    const int ln   = lane & 15;
    const int du   = lg >> 1, dv = lg & 1;

    const int bid = blockIdx.x;
    const int wg  = (bid & 7) * 128 + (bid >> 3);   // XCD swizzle (1024 % 8 == 0)
    const int n   = wg >> 5;
    const int rem = wg & 31;
    const int aq  = rem >> 2;
    const int pi  = (rem >> 1) & 1;
    const int oh  = rem & 1;
    const int a0  = aq * 4;

    const unsigned short* xpb = xp + (size_t)n * XP_N + (a0 + pi) * XP_U;
    const unsigned short* wpb = wp + pi * WP_PI + oh * 512;   // o-half within rows

    // per-lane fragment offsets (static after unroll)
    int xoff[4];
    #pragma unroll
    for (int jj = 0; jj < 4; ++jj) {
        int rr = half * 2 + (jj >> 1) + du;
        int vv = (jj & 1) * 16 + ln + pjw + dv;
        xoff[jj] = rr * XP_U + vv * 8;
    }
    const int wfoff = (pjw * 4 + lg) * WROW + ln * 8;

    f32x4 acc[4][4];
    #pragma unroll
    for (int i = 0; i < 4; ++i)
        #pragma unroll
        for (int jj = 0; jj < 4; ++jj)
            acc[i][jj] = (f32x4){0.f, 0.f, 0.f, 0.f};

    short8 xA[4], xB[4];

// 2 DMA instructions per wave per stage (wave w stages rows 2w, 2w+1; each row
// = 64 o x 8 c of this block's o-half = 512 sh = 64 lanes x 8 sh).
#define STAGE_W(CH, WBUF)                                                    \
    { const unsigned short* ws_ = wpb + (size_t)(CH) * WP_G;                 \
      unsigned short* wd_ = wsh0 + (WBUF) * WBUFS;                           \
      _Pragma("unroll")                                                      \
      for (int s_ = 0; s_ < 2; ++s_) {                                       \
          int r_ = w * 2 + s_;                                               \
          ld_lds16(ws_ + r_ * 1024 + lane * 8,                               \
                   wd_ + r_ * WROW + lane * 8); } }

#define LOAD_X(CH, XS)                                                      \
    { const unsigned short* xs_ = xpb + (size_t)(CH) * XP_G;                 \
      _Pragma("unroll")                                                      \
      for (int jj_ = 0; jj_ < 4; ++jj_)                                      \
          XS[jj_] = *(const short8*)(xs_ + xoff[jj_]); }

// Body k: wait vmcnt(VMN); barrier; [W(k+2)->buf (k+2)%3]; 16 MFMA from
// buf k%3 x XS; [x(k+2)->XS after consumption]. Ledger: 6 ops/body, steady
// wait vmcnt(6); tail 6,0.
#define CHUNK(BUF, XS, CH, VMN, DO)                                          \
    {                                                                        \
        __builtin_amdgcn_sched_barrier(0);                                   \
        asm volatile("s_waitcnt vmcnt(" #VMN ")" ::: "memory");              \
        __builtin_amdgcn_s_barrier();                                        \
        __builtin_amdgcn_sched_barrier(0);                                   \
        if (DO) STAGE_W((CH) + 2, ((BUF) + 2) % 3);                          \
        const unsigned short* wb_ = wsh0 + (BUF) * WBUFS + wfoff;            \
        _Pragma("unroll")                                                    \
        for (int i_ = 0; i_ < 4; ++i_) {                                     \
            short8 av_ = *(const short8*)&wb_[i_ * 128];                     \
            _Pragma("unroll")                                                \
            for (int jj_ = 0; jj_ < 4; ++jj_)                                \
                acc[i_][jj_] = __builtin_amdgcn_mfma_f32_16x16x32_bf16(      \
                    av_, XS[jj_], acc[i_][jj_], 0, 0, 0);                    \
        }                                                                    \
        if (DO) LOAD_X((CH) + 2, XS);                                        \
    }

    // Prologue ledger: [W0, x0, W1, x1] = 12 ops -> body 0 waits vmcnt(6).
    STAGE_W(0, 0);
    __builtin_amdgcn_sched_barrier(0);
    LOAD_X(0, xA);
    __builtin_amdgcn_sched_barrier(0);
    STAGE_W(1, 1);
    __builtin_amdgcn_sched_barrier(0);
    LOAD_X(1, xB);
    __builtin_amdgcn_sched_barrier(0);

    // Steady: body k reads buf k%3, stages W(k+2) into buf (k+2)%3 (==(k-1)%3,
    // freed — every wave's k-1 ds_reads retired before it passed barrier(k)).
    for (int c6 = 0; c6 < 30; c6 += 6) {
        CHUNK(0, xA, c6 + 0, 6, 1);
        CHUNK(1, xB, c6 + 1, 6, 1);
        CHUNK(2, xA, c6 + 2, 6, 1);
        CHUNK(0, xB, c6 + 3, 6, 1);
        CHUNK(1, xA, c6 + 4, 6, 1);
        CHUNK(2, xB, c6 + 5, 6, 1);
    }
    // Tail: before b30 queue=[W30,x30,W31,x31] -> vmcnt(6); b31 -> vmcnt(0).
    CHUNK(0, xA, 30, 6, 0);
    CHUNK(1, xB, 31, 0, 0);

#undef CHUNK
#undef LOAD_X
#undef STAGE_W

    // Epilogue (v6 conflict-free remap): write rows (r*4+lg) -> lg-quarters at
    // bank offsets 0/8/16/24; reads as float2 pairs covering all 32 banks.
    float* epi = (float*)lds;
    #pragma unroll
    for (int i = 0; i < 4; ++i) {
        __syncthreads();
        f32x4 bv = *(const f32x4*)&bias[oh * 64 + i * 16 + lg * 4];
        #pragma unroll
        for (int jj = 0; jj < 4; ++jj) {
            int ar = half * 2 + (jj >> 1);
            int b  = (jj & 1) * 16 + ln;
            #pragma unroll
            for (int r = 0; r < 4; ++r)
                epi[((r * 4 + lg) * 8 + ar * 2 + pjw) * 33 + b] = acc[i][jj][r] + bv[r];
        }
        __syncthreads();
        #pragma unroll
        for (int k = 0; k < 4; ++k) {
            int f    = tid + k * 256;    // [0,1024) float4-store ids
            int row  = f >> 4;           // o_l'(row>>2) x ar(row&3)
            int q    = f & 15;
            float2 A = *(const float2*)&epi[(row * 2 + 0) * 33 + q * 2];
            float2 B = *(const float2*)&epi[(row * 2 + 1) * 33 + q * 2];
            float4 v = { A.x, B.x, A.y, B.y };
            int olp   = row >> 2;        // o_l' = r*4 + lg
            int o     = oh * 64 + i * 16 + ((olp & 3) << 2) + (olp >> 2);
            int i_out = 2 * (a0 + (row & 3)) + pi;
            *(float4*)&out[(((size_t)n * 128 + o) * 64 + i_out) * 64 + q * 4] = v;
        }
    }
}

// =================== fallback: round-2 kernel (proven) ===================
__global__ __launch_bounds__(256) void prepack_w(const float* __restrict__ W,
                                                 unsigned short* __restrict__ Wp) {
    int t = blockIdx.x * 256 + threadIdx.x;
    int o = t >> 8, c = t & 255;
    const float4* src = (const float4*)(W + (size_t)(o * 256 + c) * 16);
    float4 q0 = src[0], q1 = src[1], q2 = src[2], q3 = src[3];
    float rows[4][4] = {{q0.x,q0.y,q0.z,q0.w},{q1.x,q1.y,q1.z,q1.w},
                        {q2.x,q2.y,q2.z,q2.w},{q3.x,q3.y,q3.z,q3.w}};
    #pragma unroll
    for (int pi = 0; pi < 2; ++pi)
    #pragma unroll
    for (int pj = 0; pj < 2; ++pj)
    #pragma unroll
    for (int du = 0; du < 2; ++du)
    #pragma unroll
    for (int dv = 0; dv < 2; ++dv)
        Wp[((((pi*2+pj)*4 + du*2+dv)*128 + o)*256) + c] = f2bf(rows[pi+2*du][pj+2*dv]);
}

template<bool PRE>
__global__ __launch_bounds__(512, 2) void tconv_mfma(
    const float* __restrict__ x, const float* __restrict__ W,
    const unsigned short* __restrict__ Wp, const float* __restrict__ bias,
    float* __restrict__ out)
{
    __shared__ __align__(16) unsigned short xsh[2][9 * 34 * 8];
    __shared__ __align__(16) unsigned short wsh[2][2 * 4 * 128 * 8];

    const int tid = threadIdx.x;
    const int bid = blockIdx.x;
    const int pi  = bid & 1;
    const int aq  = (bid >> 1) & 3;
    const int n   = bid >> 3;
    const int a0  = aq * 8;
    const int u0  = a0 + pi - 1;

    const int l   = tid & 63;
    const int w   = tid >> 6;
    const int pjw = w >> 2;
    const int q   = w & 3;
    const int lg  = l >> 4;
    const int ln  = l & 15;

    const int sv = tid & 31;
    const int sg = tid >> 5;

    f32x4 acc[8][4];
    #pragma unroll
    for (int i = 0; i < 8; ++i)
        #pragma unroll
        for (int jj = 0; jj < 4; ++jj)
            acc[i][jj] = (f32x4){0.f, 0.f, 0.f, 0.f};

    float    xv[5];
    ushort4v wv[4];
    float4   wa[2], wb[2];

    auto stage_load = [&](int ch) {
        const int c0 = ch * 8;
        #pragma unroll
        for (int s = 0; s < 5; ++s) {
            int p = sg * 5 + s;
            if (p < 72) {
                int c = p & 7, rr = p >> 3;
                int u = u0 + rr;
                xv[s] = ((unsigned)u < 32u)
                      ? x[((n*256 + c0 + c)*32 + u)*32 + sv] : 0.f;
            }
        }
        if (PRE) {
            #pragma unroll
            for (int k = 0; k < 4; ++k) {
                int uu = tid + k * 512;
                int chalf = uu & 1, o = (uu >> 1) & 127;
                int sub = (uu >> 8) & 3, pjq = (uu >> 10) & 1;
                wv[k] = *(const ushort4v*)&Wp[(((pi*2 + pjq)*4 + sub)*128 + o)*256
                                              + c0 + chalf*4];
            }
        } else {
            #pragma unroll
            for (int k = 0; k < 2; ++k) {
                int pr = tid + k * 512;
                int o = pr >> 3, c = pr & 7;
                const float* base = W + ((o*256 + c0 + c) << 4) + pi*4;
                wa[k] = *(const float4*)base;
                wb[k] = *(const float4*)(base + 8);
            }
        }
    };

    auto stage_write = [&](int buf) {
        #pragma unroll
        for (int s = 0; s < 5; ++s) {
            int p = sg * 5 + s;
            if (p < 72) {
                int c = p & 7, rr = p >> 3;
                xsh[buf][(rr*34 + sv + 1)*8 + c] = f2bf(xv[s]);
            }
        }
        if (tid < 144) {
            int pr = tid >> 1;
            int rr = pr >> 3, c = pr & 7;
            int cw = (tid & 1) * 33;
            xsh[buf][(rr*34 + cw)*8 + c] = 0;
        }
        if (PRE) {
            #pragma unroll
            for (int k = 0; k < 4; ++k) {
                int uu = tid + k * 512;
                int chalf = uu & 1, o = (uu >> 1) & 127;
                int sub = (uu >> 8) & 3, pjq = (uu >> 10) & 1;
                *(ushort4v*)&wsh[buf][(((pjq*4 + sub)*128 + o)*8) + chalf*4] = wv[k];
            }
        } else {
            #pragma unroll
            for (int k = 0; k < 2; ++k) {
                int pr = tid + k * 512;
                int o = pr >> 3, c = pr & 7;
                float ra[4] = {wa[k].x, wa[k].y, wa[k].z, wa[k].w};
                float rb[4] = {wb[k].x, wb[k].y, wb[k].z, wb[k].w};
                #pragma unroll
                for (int pj2 = 0; pj2 < 2; ++pj2)
                #pragma unroll
                for (int duu = 0; duu < 2; ++duu)
                #pragma unroll
                for (int dvv = 0; dvv < 2; ++dvv) {
                    float val = duu ? rb[pj2 + 2*dvv] : ra[pj2 + 2*dvv];
                    wsh[buf][(((pj2*4 + duu*2 + dvv)*128 + o)*8) + c] = f2bf(val);
                }
            }
        }
    };

    stage_load(0);
    stage_write(0);
    __syncthreads();

    for (int ch = 0; ch < 32; ++ch) {
        const int cur = ch & 1;
        if (ch + 1 < 32) stage_load(ch + 1);

        short8 bfr[4];
        #pragma unroll
        for (int jj = 0; jj < 4; ++jj) {
            int arow = q*2 + (jj >> 1);
            int b    = (jj & 1)*16 + ln;
            int rr   = arow + (lg >> 1);
            int cw   = b + pjw + (lg & 1);
            bfr[jj]  = *(const short8*)&xsh[cur][(rr*34 + cw)*8];
        }
        #pragma unroll
        for (int i = 0; i < 8; ++i) {
            short8 av = *(const short8*)&wsh[cur][((pjw*4 + lg)*128 + i*16 + ln)*8];
            #pragma unroll
            for (int jj = 0; jj < 4; ++jj)
                acc[i][jj] = __builtin_amdgcn_mfma_f32_16x16x32_bf16(
                                 av, bfr[jj], acc[i][jj], 0, 0, 0);
        }

        if (ch + 1 < 32) stage_write(cur ^ 1);
        __syncthreads();
    }

    #pragma unroll
    for (int i = 0; i < 8; ++i) {
        const f32x4 bv = *(const f32x4*)&bias[i*16 + lg*4];
        #pragma unroll
        for (int jj = 0; jj < 4; ++jj) {
            int arow  = q*2 + (jj >> 1);
            int b     = (jj & 1)*16 + ln;
            int i_out = 2*(a0 + arow) + pi;
            int j_out = 2*b + pjw;
            int o0    = i*16 + lg*4;
            int base  = ((n*128 + o0)*64 + i_out)*64 + j_out;
            #pragma unroll
            for (int r = 0; r < 4; ++r)
                out[base + r*4096] = acc[i][jj][r] + bv[r];
        }
    }
}

extern "C" void kernel_launch(void* const* d_in, const int* in_sizes, int n_in,
                              void* d_out, int out_size, void* d_ws, size_t ws_size,
                              hipStream_t stream) {
    const float* x    = (const float*)d_in[0];
    const float* W    = (const float*)d_in[1];
    const float* bias = (const float*)d_in[2];
    float* out        = (float*)d_out;

    const size_t wp2_bytes = (size_t)2 * WP_PI * 2;          // 1 MB
    const size_t xp_bytes  = (size_t)32 * XP_N * 2;          // ~20 MB
    if (ws_size >= wp2_bytes + xp_bytes) {
        unsigned short* wp2 = (unsigned short*)d_ws;
        unsigned short* xpp = (unsigned short*)((char*)d_ws + wp2_bytes);
        prepack_w2<<<128, 256, 0, stream>>>(W, wp2);
        prepack_x<<<dim3(34, 32), 256, 0, stream>>>(x, xpp);
        tconv_main<<<1024, 256, 0, stream>>>(xpp, wp2, bias, out);
    } else if (ws_size >= (size_t)4*4*128*256*2) {
        unsigned short* Wp = (unsigned short*)d_ws;
        prepack_w<<<128, 256, 0, stream>>>(W, Wp);
        tconv_mfma<true><<<256, 512, 0, stream>>>(x, W, Wp, bias, out);
    } else {
        tconv_mfma<false><<<256, 512, 0, stream>>>(x, W, nullptr, bias, out);
    }
}

// Round 11
// 58.113 us; speedup vs baseline: 3.2227x; 1.0917x over previous
//
#include <hip/hip_runtime.h>

// Transposed conv (stride 2, 4x4, pad 2) as bf16 MFMA implicit GEMM, v8.
// x: (32,256,32,32) f32, W: (128,256,4,4) OIHW f32, b: (128,), out: (32,128,64,64) f32
// y[n,o,2a+pi,2b+pj] = bias[o] + sum_{c,du,dv} W[o,c,pi+2du,pj+2dv] * x[n,c,a+pi-1+du,b+pj-1+dv]
//
// v8: 64o blocks (acc=64) + BK=64 phases (2 chunks per barrier, 16 barriers)
// + reg-trim to fit 128 total (=> 4 waves/SIMD, 4 blocks/CU at 32 KB LDS).
// Simple 2-buffer stage-early schedule: with 16 waves/CU the vmcnt drain at
// each barrier overlaps across co-resident blocks (m114). x B-frags stay
// global->VGPR (xp L3-resident), single base reg + imm deltas {0,128,288,416}.

typedef float  f32x4  __attribute__((ext_vector_type(4)));
typedef short  short8 __attribute__((ext_vector_type(8)));
typedef unsigned short ushort4v __attribute__((ext_vector_type(4)));
typedef unsigned short ushort8v __attribute__((ext_vector_type(8)));

__device__ __forceinline__ unsigned short f2bf(float f) {
    unsigned u = __builtin_bit_cast(unsigned, f);
    u += 0x7fffu + ((u >> 16) & 1u);          // RNE (inputs finite)
    return (unsigned short)(u >> 16);
}

__device__ __forceinline__ void ld_lds16(const unsigned short* g, unsigned short* l) {
    __builtin_amdgcn_global_load_lds(
        (const __attribute__((address_space(1))) unsigned int*)g,
        (__attribute__((address_space(3))) unsigned int*)l,
        16, 0, 0);
}

// ---------------- layout constants (ushort units) ----------------
#define XP_U 288                 // per u' row: 36 v' * 8 c
#define XP_G 9792                // per (n,g): 34 * XP_U
#define XP_N 313344              // per n: 32 g * XP_G
#define WP_G 8192                // per (pi,g): 2 pj * 4 sub * 128 o * 8 c
#define WP_PI 262144             // 32 g * WP_G

// Wp2[pi][g][pj][sub][o][c8] = bf16(W[o][g*8+c8][pi+2du][pj+2dv]), sub=2du+dv
__global__ __launch_bounds__(256) void prepack_w2(const float* __restrict__ W,
                                                  unsigned short* __restrict__ wp) {
    int t = blockIdx.x * 256 + threadIdx.x;   // (o,c) in [0, 32768)
    int o = t >> 8, c = t & 255;
    int g = c >> 3, c8 = c & 7;
    const float4* src = (const float4*)(W + (size_t)(o * 256 + c) * 16);
    float4 q0 = src[0], q1 = src[1], q2 = src[2], q3 = src[3];
    float rows[4][4] = {{q0.x,q0.y,q0.z,q0.w},{q1.x,q1.y,q1.z,q1.w},
                        {q2.x,q2.y,q2.z,q2.w},{q3.x,q3.y,q3.z,q3.w}};
    #pragma unroll
    for (int pi = 0; pi < 2; ++pi)
    #pragma unroll
    for (int pj = 0; pj < 2; ++pj)
    #pragma unroll
    for (int du = 0; du < 2; ++du)
    #pragma unroll
    for (int dv = 0; dv < 2; ++dv)
        wp[pi*WP_PI + g*WP_G + pj*4096 + (du*2+dv)*1024 + o*8 + c8] =
            f2bf(rows[pi+2*du][pj+2*dv]);
}

// xp[n][g][u'][v'][c8] = bf16(x[n][g*8+c8][u'-1][v'-1]); u'/v' out of range -> 0.
__global__ __launch_bounds__(256) void prepack_x(const float* __restrict__ x,
                                                 unsigned short* __restrict__ xp) {
    __shared__ unsigned short xt[256 * 32];   // [c][v] bf16, 16 KB
    const int tid = threadIdx.x;
    const int up  = blockIdx.x;               // u' in [0,34)
    const int n   = blockIdx.y;
    const bool interior = (up >= 1 && up <= 32);

    if (interior) {
        const int u = up - 1;
        #pragma unroll
        for (int k = 0; k < 8; ++k) {
            int idx4 = tid + k * 256;          // [0,2048) float4 units
            int c = idx4 >> 3, v4 = idx4 & 7;
            float4 val = *(const float4*)(x + ((size_t)(n*256 + c)*32 + u)*32 + v4*4);
            ushort4v s = { f2bf(val.x), f2bf(val.y), f2bf(val.z), f2bf(val.w) };
            *(ushort4v*)&xt[c*32 + v4*4] = s;
        }
        __syncthreads();
    }

    #pragma unroll
    for (int s = 0; s < 5; ++s) {
        int id = tid + s * 256;                // (g, v') in [0, 32*36)
        if (id < 1152) {
            int g = id / 36, vp = id % 36;
            ushort8v o8 = {0,0,0,0,0,0,0,0};
            if (interior && vp >= 1 && vp <= 32) {      // v = vp-1 in [0,32)
                #pragma unroll
                for (int e = 0; e < 8; ++e)
                    o8[e] = xt[(g*8 + e)*32 + (vp - 1)];
            }
            *(ushort8v*)&xp[(size_t)n*XP_N + g*XP_G + up*XP_U + vp*8] = o8;
        }
    }
}

// Main: grid 1024 = (n, aq in [0,8), pi, oh), XCD-swizzled. 256 thr = 4 waves
// (pjw, half). Block tile: 64 o x (4 arows x 32 b x 2 pj). Wave: 64o x 64px.
// 16 phases; phase p = chunks {2p, 2p+1}.
__global__ __launch_bounds__(256, 4) void tconv_main(
    const unsigned short* __restrict__ xp,
    const unsigned short* __restrict__ wp,
    const float* __restrict__ bias,
    float* __restrict__ out)
{
    // W: 2 phase-buffers x [2 chunks][8 rows][512 sh] = 16384 sh = 32768 B.
    // Epilogue (16.9 KB f32) overlays.
    __shared__ __align__(16) unsigned short lds[16384];

    const int tid  = threadIdx.x;
    const int lane = tid & 63;
    const int w    = tid >> 6;       // wave 0..3
    const int pjw  = w >> 1;
    const int half = w & 1;
    const int lg   = lane >> 4;      // sub = (du,dv)
    const int ln   = lane & 15;
    const int du   = lg >> 1, dv = lg & 1;

    const int bid = blockIdx.x;
    const int wg  = (bid & 7) * 128 + (bid >> 3);   // XCD swizzle (1024 % 8 == 0)
    const int n   = wg >> 5;
    const int rem = wg & 31;
    const int aq  = rem >> 2;
    const int pi  = (rem >> 1) & 1;
    const int oh  = rem & 1;
    const int a0  = aq * 4;

    const unsigned short* xpb = xp + (size_t)n * XP_N + (a0 + pi) * XP_U
                              + ((half * 2 + du) * XP_U + (ln + pjw + dv) * 8); // + xoff0
    const unsigned short* wpb = wp + pi * WP_PI + oh * 512;   // o-half within rows

    const int wfoff = (pjw * 4 + lg) * 512 + ln * 8;

    f32x4 acc[4][4];
    #pragma unroll
    for (int i = 0; i < 4; ++i)
        #pragma unroll
        for (int jj = 0; jj < 4; ++jj)
            acc[i][jj] = (f32x4){0.f, 0.f, 0.f, 0.f};

    short8 xA[4], xB[4];

// Stage phase P's W (chunks 2P, 2P+1) into buffer BUF: 4 DMA/wave.
#define STAGE_W(P, BUF)                                                      \
    { _Pragma("unroll")                                                      \
      for (int cc_ = 0; cc_ < 2; ++cc_) {                                    \
        const unsigned short* ws_ = wpb + (size_t)(2*(P) + cc_) * WP_G;      \
        unsigned short* wd_ = (unsigned short*)lds + (BUF)*8192 + cc_*4096;  \
        _Pragma("unroll")                                                    \
        for (int s_ = 0; s_ < 2; ++s_) {                                     \
            int r_ = w * 2 + s_;                                             \
            ld_lds16(ws_ + r_ * 1024 + lane * 8,                             \
                     wd_ + r_ * 512 + lane * 8); } } }

// x fragment for chunk CH -> XS (4x global dwordx4; deltas are imm offsets).
#define LOAD_X(CH, XS)                                                      \
    { const unsigned short* xs_ = xpb + (size_t)(CH) * XP_G;                 \
      XS[0] = *(const short8*)(xs_);                                         \
      XS[1] = *(const short8*)(xs_ + 128);                                   \
      XS[2] = *(const short8*)(xs_ + XP_U);                                  \
      XS[3] = *(const short8*)(xs_ + XP_U + 128); }

// 16 MFMA for one chunk-slot CC of buffer BUF against XS.
#define MFMA_CHUNK(BUF, CC, XS)                                              \
    { const unsigned short* wb_ = (unsigned short*)lds + (BUF)*8192          \
                                  + (CC)*4096 + wfoff;                       \
      _Pragma("unroll")                                                      \
      for (int i_ = 0; i_ < 4; ++i_) {                                       \
          short8 av_ = *(const short8*)&wb_[i_ * 128];                       \
          _Pragma("unroll")                                                  \
          for (int jj_ = 0; jj_ < 4; ++jj_)                                  \
              acc[i_][jj_] = __builtin_amdgcn_mfma_f32_16x16x32_bf16(        \
                  av_, XS[jj_], acc[i_][jj_], 0, 0, 0);                      \
      } }

    // Prologue: stage phase 0, load x(0), x(1).
    STAGE_W(0, 0);
    __builtin_amdgcn_sched_barrier(0);
    LOAD_X(0, xA);
    LOAD_X(1, xB);
    __syncthreads();                      // drains vmcnt(0): buf0 + xA/xB ready

    for (int p = 0; p < 16; ++p) {
        const int cur = p & 1;
        if (p < 15) {
            STAGE_W(p + 1, cur ^ 1);      // issue early — lands by next barrier
            __builtin_amdgcn_sched_barrier(0);
        }
        MFMA_CHUNK(cur, 0, xA);
        if (p < 15) LOAD_X(2 * p + 2, xA);
        MFMA_CHUNK(cur, 1, xB);
        if (p < 15) LOAD_X(2 * p + 3, xB);
        __syncthreads();                  // drain: next-phase W + x landed
    }

#undef MFMA_CHUNK
#undef LOAD_X
#undef STAGE_W

    // Epilogue (v7 conflict-free remap, correctness-proven): write rows
    // (r*4+lg) -> lg-quarters at bank offsets 0/8/16/24; float2-pair reads.
    float* epi = (float*)lds;
    #pragma unroll
    for (int i = 0; i < 4; ++i) {
        __syncthreads();
        f32x4 bv = *(const f32x4*)&bias[oh * 64 + i * 16 + lg * 4];
        #pragma unroll
        for (int jj = 0; jj < 4; ++jj) {
            int ar = half * 2 + (jj >> 1);
            int b  = (jj & 1) * 16 + ln;
            #pragma unroll
            for (int r = 0; r < 4; ++r)
                epi[((r * 4 + lg) * 8 + ar * 2 + pjw) * 33 + b] = acc[i][jj][r] + bv[r];
        }
        __syncthreads();
        #pragma unroll
        for (int k = 0; k < 4; ++k) {
            int f    = tid + k * 256;    // [0,1024) float4-store ids
            int row  = f >> 4;           // o_l'(row>>2) x ar(row&3)
            int q    = f & 15;
            float2 A = *(const float2*)&epi[(row * 2 + 0) * 33 + q * 2];
            float2 B = *(const float2*)&epi[(row * 2 + 1) * 33 + q * 2];
            float4 v = { A.x, B.x, A.y, B.y };
            int olp   = row >> 2;        // o_l' = r*4 + lg
            int o     = oh * 64 + i * 16 + ((olp & 3) << 2) + (olp >> 2);
            int i_out = 2 * (a0 + (row & 3)) + pi;
            *(float4*)&out[(((size_t)n * 128 + o) * 64 + i_out) * 64 + q * 4] = v;
        }
    }
}

// =================== fallback: round-2 kernel (proven) ===================
__global__ __launch_bounds__(256) void prepack_w(const float* __restrict__ W,
                                                 unsigned short* __restrict__ Wp) {
    int t = blockIdx.x * 256 + threadIdx.x;
    int o = t >> 8, c = t & 255;
    const float4* src = (const float4*)(W + (size_t)(o * 256 + c) * 16);
    float4 q0 = src[0], q1 = src[1], q2 = src[2], q3 = src[3];
    float rows[4][4] = {{q0.x,q0.y,q0.z,q0.w},{q1.x,q1.y,q1.z,q1.w},
                        {q2.x,q2.y,q2.z,q2.w},{q3.x,q3.y,q3.z,q3.w}};
    #pragma unroll
    for (int pi = 0; pi < 2; ++pi)
    #pragma unroll
    for (int pj = 0; pj < 2; ++pj)
    #pragma unroll
    for (int du = 0; du < 2; ++du)
    #pragma unroll
    for (int dv = 0; dv < 2; ++dv)
        Wp[((((pi*2+pj)*4 + du*2+dv)*128 + o)*256) + c] = f2bf(rows[pi+2*du][pj+2*dv]);
}

template<bool PRE>
__global__ __launch_bounds__(512, 2) void tconv_mfma(
    const float* __restrict__ x, const float* __restrict__ W,
    const unsigned short* __restrict__ Wp, const float* __restrict__ bias,
    float* __restrict__ out)
{
    __shared__ __align__(16) unsigned short xsh[2][9 * 34 * 8];
    __shared__ __align__(16) unsigned short wsh[2][2 * 4 * 128 * 8];

    const int tid = threadIdx.x;
    const int bid = blockIdx.x;
    const int pi  = bid & 1;
    const int aq  = (bid >> 1) & 3;
    const int n   = bid >> 3;
    const int a0  = aq * 8;
    const int u0  = a0 + pi - 1;

    const int l   = tid & 63;
    const int w   = tid >> 6;
    const int pjw = w >> 2;
    const int q   = w & 3;
    const int lg  = l >> 4;
    const int ln  = l & 15;

    const int sv = tid & 31;
    const int sg = tid >> 5;

    f32x4 acc[8][4];
    #pragma unroll
    for (int i = 0; i < 8; ++i)
        #pragma unroll
        for (int jj = 0; jj < 4; ++jj)
            acc[i][jj] = (f32x4){0.f, 0.f, 0.f, 0.f};

    float    xv[5];
    ushort4v wv[4];
    float4   wa[2], wb[2];

    auto stage_load = [&](int ch) {
        const int c0 = ch * 8;
        #pragma unroll
        for (int s = 0; s < 5; ++s) {
            int p = sg * 5 + s;
            if (p < 72) {
                int c = p & 7, rr = p >> 3;
                int u = u0 + rr;
                xv[s] = ((unsigned)u < 32u)
                      ? x[((n*256 + c0 + c)*32 + u)*32 + sv] : 0.f;
            }
        }
        if (PRE) {
            #pragma unroll
            for (int k = 0; k < 4; ++k) {
                int uu = tid + k * 512;
                int chalf = uu & 1, o = (uu >> 1) & 127;
                int sub = (uu >> 8) & 3, pjq = (uu >> 10) & 1;
                wv[k] = *(const ushort4v*)&Wp[(((pi*2 + pjq)*4 + sub)*128 + o)*256
                                              + c0 + chalf*4];
            }
        } else {
            #pragma unroll
            for (int k = 0; k < 2; ++k) {
                int pr = tid + k * 512;
                int o = pr >> 3, c = pr & 7;
                const float* base = W + ((o*256 + c0 + c) << 4) + pi*4;
                wa[k] = *(const float4*)base;
                wb[k] = *(const float4*)(base + 8);
            }
        }
    };

    auto stage_write = [&](int buf) {
        #pragma unroll
        for (int s = 0; s < 5; ++s) {
            int p = sg * 5 + s;
            if (p < 72) {
                int c = p & 7, rr = p >> 3;
                xsh[buf][(rr*34 + sv + 1)*8 + c] = f2bf(xv[s]);
            }
        }
        if (tid < 144) {
            int pr = tid >> 1;
            int rr = pr >> 3, c = pr & 7;
            int cw = (tid & 1) * 33;
            xsh[buf][(rr*34 + cw)*8 + c] = 0;
        }
        if (PRE) {
            #pragma unroll
            for (int k = 0; k < 4; ++k) {
                int uu = tid + k * 512;
                int chalf = uu & 1, o = (uu >> 1) & 127;
                int sub = (uu >> 8) & 3, pjq = (uu >> 10) & 1;
                *(ushort4v*)&wsh[buf][(((pjq*4 + sub)*128 + o)*8) + chalf*4] = wv[k];
            }
        } else {
            #pragma unroll
            for (int k = 0; k < 2; ++k) {
                int pr = tid + k * 512;
                int o = pr >> 3, c = pr & 7;
                float ra[4] = {wa[k].x, wa[k].y, wa[k].z, wa[k].w};
                float rb[4] = {wb[k].x, wb[k].y, wb[k].z, wb[k].w};
                #pragma unroll
                for (int pj2 = 0; pj2 < 2; ++pj2)
                #pragma unroll
                for (int duu = 0; duu < 2; ++duu)
                #pragma unroll
                for (int dvv = 0; dvv < 2; ++dvv) {
                    float val = duu ? rb[pj2 + 2*dvv] : ra[pj2 + 2*dvv];
                    wsh[buf][(((pj2*4 + duu*2 + dvv)*128 + o)*8) + c] = f2bf(val);
                }
            }
        }
    };

    stage_load(0);
    stage_write(0);
    __syncthreads();

    for (int ch = 0; ch < 32; ++ch) {
        const int cur = ch & 1;
        if (ch + 1 < 32) stage_load(ch + 1);

        short8 bfr[4];
        #pragma unroll
        for (int jj = 0; jj < 4; ++jj) {
            int arow = q*2 + (jj >> 1);
            int b    = (jj & 1)*16 + ln;
            int rr   = arow + (lg >> 1);
            int cw   = b + pjw + (lg & 1);
            bfr[jj]  = *(const short8*)&xsh[cur][(rr*34 + cw)*8];
        }
        #pragma unroll
        for (int i = 0; i < 8; ++i) {
            short8 av = *(const short8*)&wsh[cur][((pjw*4 + lg)*128 + i*16 + ln)*8];
            #pragma unroll
            for (int jj = 0; jj < 4; ++jj)
                acc[i][jj] = __builtin_amdgcn_mfma_f32_16x16x32_bf16(
                                 av, bfr[jj], acc[i][jj], 0, 0, 0);
        }

        if (ch + 1 < 32) stage_write(cur ^ 1);
        __syncthreads();
    }

    #pragma unroll
    for (int i = 0; i < 8; ++i) {
        const f32x4 bv = *(const f32x4*)&bias[i*16 + lg*4];
        #pragma unroll
        for (int jj = 0; jj < 4; ++jj) {
            int arow  = q*2 + (jj >> 1);
            int b     = (jj & 1)*16 + ln;
            int i_out = 2*(a0 + arow) + pi;
            int j_out = 2*b + pjw;
            int o0    = i*16 + lg*4;
            int base  = ((n*128 + o0)*64 + i_out)*64 + j_out;
            #pragma unroll
            for (int r = 0; r < 4; ++r)
                out[base + r*4096] = acc[i][jj][r] + bv[r];
        }
    }
}

extern "C" void kernel_launch(void* const* d_in, const int* in_sizes, int n_in,
                              void* d_out, int out_size, void* d_ws, size_t ws_size,
                              hipStream_t stream) {
    const float* x    = (const float*)d_in[0];
    const float* W    = (const float*)d_in[1];
    const float* bias = (const float*)d_in[2];
    float* out        = (float*)d_out;

    const size_t wp2_bytes = (size_t)2 * WP_PI * 2;          // 1 MB
    const size_t xp_bytes  = (size_t)32 * XP_N * 2;          // ~20 MB
    if (ws_size >= wp2_bytes + xp_bytes) {
        unsigned short* wp2 = (unsigned short*)d_ws;
        unsigned short* xpp = (unsigned short*)((char*)d_ws + wp2_bytes);
        prepack_w2<<<128, 256, 0, stream>>>(W, wp2);
        prepack_x<<<dim3(34, 32), 256, 0, stream>>>(x, xpp);
        tconv_main<<<1024, 256, 0, stream>>>(xpp, wp2, bias, out);
    } else if (ws_size >= (size_t)4*4*128*256*2) {
        unsigned short* Wp = (unsigned short*)d_ws;
        prepack_w<<<128, 256, 0, stream>>>(W, Wp);
        tconv_mfma<true><<<256, 512, 0, stream>>>(x, W, Wp, bias, out);
    } else {
        tconv_mfma<false><<<256, 512, 0, stream>>>(x, W, nullptr, bias, out);
    }
}

// Round 12
// 57.788 us; speedup vs baseline: 3.2408x; 1.0056x over previous
//
#include <hip/hip_runtime.h>

// Transposed conv (stride 2, 4x4, pad 2) as bf16 MFMA implicit GEMM, v9.
// x: (32,256,32,32) f32, W: (128,256,4,4) OIHW f32, b: (128,), out: (32,128,64,64) f32
// y[n,o,2a+pi,2b+pj] = bias[o] + sum_{c,du,dv} W[o,c,pi+2du,pj+2dv] * x[n,c,a+pi-1+du,b+pj-1+dv]
//
// v9 = v8 geometry + v5 schedule:
//   geometry: 64o blocks (acc=64, 128 regs total -> 4 waves/SIMD), BK=64
//   phases (2 chunks/barrier), 2x16KB W buffers (32 KB LDS -> 4 blocks/CU).
//   schedule: counted-vmcnt ledger, NEVER vmcnt(0) in the loop. Per wave per
//   phase: header [vmcnt(8) retires own W(p); s_barrier -> all waves' W(p)
//   landed], body [stage W(p+1): 4 DMA; MFMA c0; load x(2p+2); MFMA c1;
//   load x(2p+3)] -> 12 outstanding at phase end. T5 setprio around MFMAs.

typedef float  f32x4  __attribute__((ext_vector_type(4)));
typedef short  short8 __attribute__((ext_vector_type(8)));
typedef unsigned short ushort4v __attribute__((ext_vector_type(4)));
typedef unsigned short ushort8v __attribute__((ext_vector_type(8)));

__device__ __forceinline__ unsigned short f2bf(float f) {
    unsigned u = __builtin_bit_cast(unsigned, f);
    u += 0x7fffu + ((u >> 16) & 1u);          // RNE (inputs finite)
    return (unsigned short)(u >> 16);
}

__device__ __forceinline__ void ld_lds16(const unsigned short* g, unsigned short* l) {
    __builtin_amdgcn_global_load_lds(
        (const __attribute__((address_space(1))) unsigned int*)g,
        (__attribute__((address_space(3))) unsigned int*)l,
        16, 0, 0);
}

// ---------------- layout constants (ushort units) ----------------
#define XP_U 288                 // per u' row: 36 v' * 8 c
#define XP_G 9792                // per (n,g): 34 * XP_U
#define XP_N 313344              // per n: 32 g * XP_G
#define WP_G 8192                // per (pi,g): 2 pj * 4 sub * 128 o * 8 c
#define WP_PI 262144             // 32 g * WP_G

// Wp2[pi][g][pj][sub][o][c8] = bf16(W[o][g*8+c8][pi+2du][pj+2dv]), sub=2du+dv
__global__ __launch_bounds__(256) void prepack_w2(const float* __restrict__ W,
                                                  unsigned short* __restrict__ wp) {
    int t = blockIdx.x * 256 + threadIdx.x;   // (o,c) in [0, 32768)
    int o = t >> 8, c = t & 255;
    int g = c >> 3, c8 = c & 7;
    const float4* src = (const float4*)(W + (size_t)(o * 256 + c) * 16);
    float4 q0 = src[0], q1 = src[1], q2 = src[2], q3 = src[3];
    float rows[4][4] = {{q0.x,q0.y,q0.z,q0.w},{q1.x,q1.y,q1.z,q1.w},
                        {q2.x,q2.y,q2.z,q2.w},{q3.x,q3.y,q3.z,q3.w}};
    #pragma unroll
    for (int pi = 0; pi < 2; ++pi)
    #pragma unroll
    for (int pj = 0; pj < 2; ++pj)
    #pragma unroll
    for (int du = 0; du < 2; ++du)
    #pragma unroll
    for (int dv = 0; dv < 2; ++dv)
        wp[pi*WP_PI + g*WP_G + pj*4096 + (du*2+dv)*1024 + o*8 + c8] =
            f2bf(rows[pi+2*du][pj+2*dv]);
}

// xp[n][g][u'][v'][c8] = bf16(x[n][g*8+c8][u'-1][v'-1]); u'/v' out of range -> 0.
__global__ __launch_bounds__(256) void prepack_x(const float* __restrict__ x,
                                                 unsigned short* __restrict__ xp) {
    __shared__ unsigned short xt[256 * 32];   // [c][v] bf16, 16 KB
    const int tid = threadIdx.x;
    const int up  = blockIdx.x;               // u' in [0,34)
    const int n   = blockIdx.y;
    const bool interior = (up >= 1 && up <= 32);

    if (interior) {
        const int u = up - 1;
        #pragma unroll
        for (int k = 0; k < 8; ++k) {
            int idx4 = tid + k * 256;          // [0,2048) float4 units
            int c = idx4 >> 3, v4 = idx4 & 7;
            float4 val = *(const float4*)(x + ((size_t)(n*256 + c)*32 + u)*32 + v4*4);
            ushort4v s = { f2bf(val.x), f2bf(val.y), f2bf(val.z), f2bf(val.w) };
            *(ushort4v*)&xt[c*32 + v4*4] = s;
        }
        __syncthreads();
    }

    #pragma unroll
    for (int s = 0; s < 5; ++s) {
        int id = tid + s * 256;                // (g, v') in [0, 32*36)
        if (id < 1152) {
            int g = id / 36, vp = id % 36;
            ushort8v o8 = {0,0,0,0,0,0,0,0};
            if (interior && vp >= 1 && vp <= 32) {      // v = vp-1 in [0,32)
                #pragma unroll
                for (int e = 0; e < 8; ++e)
                    o8[e] = xt[(g*8 + e)*32 + (vp - 1)];
            }
            *(ushort8v*)&xp[(size_t)n*XP_N + g*XP_G + up*XP_U + vp*8] = o8;
        }
    }
}

// Main: grid 1024 = (n, aq in [0,8), pi, oh), XCD-swizzled. 256 thr = 4 waves
// (pjw, half). Block tile: 64 o x (4 arows x 32 b x 2 pj). Wave: 64o x 64px.
// 16 phases; phase p = chunks {2p, 2p+1}.
__global__ __launch_bounds__(256, 4) void tconv_main(
    const unsigned short* __restrict__ xp,
    const unsigned short* __restrict__ wp,
    const float* __restrict__ bias,
    float* __restrict__ out)
{
    // W: 2 phase-buffers x [2 chunks][8 rows][512 sh] = 16384 sh = 32768 B.
    // Epilogue (16.9 KB f32) overlays.
    __shared__ __align__(16) unsigned short lds[16384];

    const int tid  = threadIdx.x;
    const int lane = tid & 63;
    const int w    = tid >> 6;       // wave 0..3
    const int pjw  = w >> 1;
    const int half = w & 1;
    const int lg   = lane >> 4;      // sub = (du,dv)
    const int ln   = lane & 15;
    const int du   = lg >> 1, dv = lg & 1;

    const int bid = blockIdx.x;
    const int wg  = (bid & 7) * 128 + (bid >> 3);   // XCD swizzle (1024 % 8 == 0)
    const int n   = wg >> 5;
    const int rem = wg & 31;
    const int aq  = rem >> 2;
    const int pi  = (rem >> 1) & 1;
    const int oh  = rem & 1;
    const int a0  = aq * 4;

    const unsigned short* xpb = xp + (size_t)n * XP_N + (a0 + pi) * XP_U
                              + ((half * 2 + du) * XP_U + (ln + pjw + dv) * 8); // + xoff0
    const unsigned short* wpb = wp + pi * WP_PI + oh * 512;   // o-half within rows

    const int wfoff = (pjw * 4 + lg) * 512 + ln * 8;

    f32x4 acc[4][4];
    #pragma unroll
    for (int i = 0; i < 4; ++i)
        #pragma unroll
        for (int jj = 0; jj < 4; ++jj)
            acc[i][jj] = (f32x4){0.f, 0.f, 0.f, 0.f};

    short8 xA[4], xB[4];

// Stage phase P's W (chunks 2P, 2P+1) into buffer BUF: 4 DMA/wave.
#define STAGE_W(P, BUF)                                                      \
    { _Pragma("unroll")                                                      \
      for (int cc_ = 0; cc_ < 2; ++cc_) {                                    \
        const unsigned short* ws_ = wpb + (size_t)(2*(P) + cc_) * WP_G;      \
        unsigned short* wd_ = (unsigned short*)lds + (BUF)*8192 + cc_*4096;  \
        _Pragma("unroll")                                                    \
        for (int s_ = 0; s_ < 2; ++s_) {                                     \
            int r_ = w * 2 + s_;                                             \
            ld_lds16(ws_ + r_ * 1024 + lane * 8,                             \
                     wd_ + r_ * 512 + lane * 8); } } }

// x fragment for chunk CH -> XS (4x global dwordx4; deltas are imm offsets).
#define LOAD_X(CH, XS)                                                      \
    { const unsigned short* xs_ = xpb + (size_t)(CH) * XP_G;                 \
      XS[0] = *(const short8*)(xs_);                                         \
      XS[1] = *(const short8*)(xs_ + 128);                                   \
      XS[2] = *(const short8*)(xs_ + XP_U);                                  \
      XS[3] = *(const short8*)(xs_ + XP_U + 128); }

// 16 MFMA for one chunk-slot CC of buffer BUF against XS (T5 setprio).
#define MFMA_CHUNK(BUF, CC, XS)                                              \
    { const unsigned short* wb_ = (unsigned short*)lds + (BUF)*8192          \
                                  + (CC)*4096 + wfoff;                       \
      __builtin_amdgcn_s_setprio(1);                                        \
      _Pragma("unroll")                                                      \
      for (int i_ = 0; i_ < 4; ++i_) {                                       \
          short8 av_ = *(const short8*)&wb_[i_ * 128];                       \
          _Pragma("unroll")                                                  \
          for (int jj_ = 0; jj_ < 4; ++jj_)                                  \
              acc[i_][jj_] = __builtin_amdgcn_mfma_f32_16x16x32_bf16(        \
                  av_, XS[jj_], acc[i_][jj_], 0, 0, 0);                      \
      }                                                                      \
      __builtin_amdgcn_s_setprio(0); }

// Phase header: retire own W(p) (8 newer x-ops stay in flight), then barrier
// -> all waves' W(p) landed (each waited before its barrier arrival).
#define PHASE_HDR()                                                          \
    __builtin_amdgcn_sched_barrier(0);                                       \
    asm volatile("s_waitcnt vmcnt(8)" ::: "memory");                         \
    __builtin_amdgcn_s_barrier();                                            \
    __builtin_amdgcn_sched_barrier(0);

// Full phase p (p < 15): ledger entry 12 = [W(p):4, x(2p):4, x(2p+1):4].
#define PHASE_FULL(CUR, P)                                                   \
    {                                                                        \
        PHASE_HDR();                                                         \
        STAGE_W((P) + 1, (CUR) ^ 1);                                         \
        __builtin_amdgcn_sched_barrier(0);                                   \
        MFMA_CHUNK(CUR, 0, xA);                                              \
        LOAD_X(2 * (P) + 2, xA);                                             \
        MFMA_CHUNK(CUR, 1, xB);                                              \
        LOAD_X(2 * (P) + 3, xB);                                             \
    }

    // Prologue ledger: [W(0):4, x(0):4, x(1):4] = 12 outstanding.
    STAGE_W(0, 0);
    __builtin_amdgcn_sched_barrier(0);
    LOAD_X(0, xA);
    LOAD_X(1, xB);

    for (int pp = 0; pp < 14; pp += 2) {
        PHASE_FULL(0, pp);
        PHASE_FULL(1, pp + 1);
    }
    PHASE_FULL(0, 14);
    // Tail phase 15: entry = [W(15):4, x(30):4, x(31):4]; no new issues;
    // compiler's own waits drain x (vmcnt 4 then 0).
    PHASE_HDR();
    MFMA_CHUNK(1, 0, xA);
    MFMA_CHUNK(1, 1, xB);

#undef PHASE_FULL
#undef PHASE_HDR
#undef MFMA_CHUNK
#undef LOAD_X
#undef STAGE_W

    __syncthreads();   // before LDS reuse by epilogue

    // Epilogue (proven remap): write rows (r*4+lg) -> lg-quarters at bank
    // offsets 0/8/16/24; float2-pair reads cover all 32 banks per instr.
    float* epi = (float*)lds;
    #pragma unroll
    for (int i = 0; i < 4; ++i) {
        __syncthreads();
        f32x4 bv = *(const f32x4*)&bias[oh * 64 + i * 16 + lg * 4];
        #pragma unroll
        for (int jj = 0; jj < 4; ++jj) {
            int ar = half * 2 + (jj >> 1);
            int b  = (jj & 1) * 16 + ln;
            #pragma unroll
            for (int r = 0; r < 4; ++r)
                epi[((r * 4 + lg) * 8 + ar * 2 + pjw) * 33 + b] = acc[i][jj][r] + bv[r];
        }
        __syncthreads();
        #pragma unroll
        for (int k = 0; k < 4; ++k) {
            int f    = tid + k * 256;    // [0,1024) float4-store ids
            int row  = f >> 4;           // o_l'(row>>2) x ar(row&3)
            int q    = f & 15;
            float2 A = *(const float2*)&epi[(row * 2 + 0) * 33 + q * 2];
            float2 B = *(const float2*)&epi[(row * 2 + 1) * 33 + q * 2];
            float4 v = { A.x, B.x, A.y, B.y };
            int olp   = row >> 2;        // o_l' = r*4 + lg
            int o     = oh * 64 + i * 16 + ((olp & 3) << 2) + (olp >> 2);
            int i_out = 2 * (a0 + (row & 3)) + pi;
            *(float4*)&out[(((size_t)n * 128 + o) * 64 + i_out) * 64 + q * 4] = v;
        }
    }
}

// =================== fallback: round-2 kernel (proven) ===================
__global__ __launch_bounds__(256) void prepack_w(const float* __restrict__ W,
                                                 unsigned short* __restrict__ Wp) {
    int t = blockIdx.x * 256 + threadIdx.x;
    int o = t >> 8, c = t & 255;
    const float4* src = (const float4*)(W + (size_t)(o * 256 + c) * 16);
    float4 q0 = src[0], q1 = src[1], q2 = src[2], q3 = src[3];
    float rows[4][4] = {{q0.x,q0.y,q0.z,q0.w},{q1.x,q1.y,q1.z,q1.w},
                        {q2.x,q2.y,q2.z,q2.w},{q3.x,q3.y,q3.z,q3.w}};
    #pragma unroll
    for (int pi = 0; pi < 2; ++pi)
    #pragma unroll
    for (int pj = 0; pj < 2; ++pj)
    #pragma unroll
    for (int du = 0; du < 2; ++du)
    #pragma unroll
    for (int dv = 0; dv < 2; ++dv)
        Wp[((((pi*2+pj)*4 + du*2+dv)*128 + o)*256) + c] = f2bf(rows[pi+2*du][pj+2*dv]);
}

template<bool PRE>
__global__ __launch_bounds__(512, 2) void tconv_mfma(
    const float* __restrict__ x, const float* __restrict__ W,
    const unsigned short* __restrict__ Wp, const float* __restrict__ bias,
    float* __restrict__ out)
{
    __shared__ __align__(16) unsigned short xsh[2][9 * 34 * 8];
    __shared__ __align__(16) unsigned short wsh[2][2 * 4 * 128 * 8];

    const int tid = threadIdx.x;
    const int bid = blockIdx.x;
    const int pi  = bid & 1;
    const int aq  = (bid >> 1) & 3;
    const int n   = bid >> 3;
    const int a0  = aq * 8;
    const int u0  = a0 + pi - 1;

    const int l   = tid & 63;
    const int w   = tid >> 6;
    const int pjw = w >> 2;
    const int q   = w & 3;
    const int lg  = l >> 4;
    const int ln  = l & 15;

    const int sv = tid & 31;
    const int sg = tid >> 5;

    f32x4 acc[8][4];
    #pragma unroll
    for (int i = 0; i < 8; ++i)
        #pragma unroll
        for (int jj = 0; jj < 4; ++jj)
            acc[i][jj] = (f32x4){0.f, 0.f, 0.f, 0.f};

    float    xv[5];
    ushort4v wv[4];
    float4   wa[2], wb[2];

    auto stage_load = [&](int ch) {
        const int c0 = ch * 8;
        #pragma unroll
        for (int s = 0; s < 5; ++s) {
            int p = sg * 5 + s;
            if (p < 72) {
                int c = p & 7, rr = p >> 3;
                int u = u0 + rr;
                xv[s] = ((unsigned)u < 32u)
                      ? x[((n*256 + c0 + c)*32 + u)*32 + sv] : 0.f;
            }
        }
        if (PRE) {
            #pragma unroll
            for (int k = 0; k < 4; ++k) {
                int uu = tid + k * 512;
                int chalf = uu & 1, o = (uu >> 1) & 127;
                int sub = (uu >> 8) & 3, pjq = (uu >> 10) & 1;
                wv[k] = *(const ushort4v*)&Wp[(((pi*2 + pjq)*4 + sub)*128 + o)*256
                                              + c0 + chalf*4];
            }
        } else {
            #pragma unroll
            for (int k = 0; k < 2; ++k) {
                int pr = tid + k * 512;
                int o = pr >> 3, c = pr & 7;
                const float* base = W + ((o*256 + c0 + c) << 4) + pi*4;
                wa[k] = *(const float4*)base;
                wb[k] = *(const float4*)(base + 8);
            }
        }
    };

    auto stage_write = [&](int buf) {
        #pragma unroll
        for (int s = 0; s < 5; ++s) {
            int p = sg * 5 + s;
            if (p < 72) {
                int c = p & 7, rr = p >> 3;
                xsh[buf][(rr*34 + sv + 1)*8 + c] = f2bf(xv[s]);
            }
        }
        if (tid < 144) {
            int pr = tid >> 1;
            int rr = pr >> 3, c = pr & 7;
            int cw = (tid & 1) * 33;
            xsh[buf][(rr*34 + cw)*8 + c] = 0;
        }
        if (PRE) {
            #pragma unroll
            for (int k = 0; k < 4; ++k) {
                int uu = tid + k * 512;
                int chalf = uu & 1, o = (uu >> 1) & 127;
                int sub = (uu >> 8) & 3, pjq = (uu >> 10) & 1;
                *(ushort4v*)&wsh[buf][(((pjq*4 + sub)*128 + o)*8) + chalf*4] = wv[k];
            }
        } else {
            #pragma unroll
            for (int k = 0; k < 2; ++k) {
                int pr = tid + k * 512;
                int o = pr >> 3, c = pr & 7;
                float ra[4] = {wa[k].x, wa[k].y, wa[k].z, wa[k].w};
                float rb[4] = {wb[k].x, wb[k].y, wb[k].z, wb[k].w};
                #pragma unroll
                for (int pj2 = 0; pj2 < 2; ++pj2)
                #pragma unroll
                for (int duu = 0; duu < 2; ++duu)
                #pragma unroll
                for (int dvv = 0; dvv < 2; ++dvv) {
                    float val = duu ? rb[pj2 + 2*dvv] : ra[pj2 + 2*dvv];
                    wsh[buf][(((pj2*4 + duu*2 + dvv)*128 + o)*8) + c] = f2bf(val);
                }
            }
        }
    };

    stage_load(0);
    stage_write(0);
    __syncthreads();

    for (int ch = 0; ch < 32; ++ch) {
        const int cur = ch & 1;
        if (ch + 1 < 32) stage_load(ch + 1);

        short8 bfr[4];
        #pragma unroll
        for (int jj = 0; jj < 4; ++jj) {
            int arow = q*2 + (jj >> 1);
            int b    = (jj & 1)*16 + ln;
            int rr   = arow + (lg >> 1);
            int cw   = b + pjw + (lg & 1);
            bfr[jj]  = *(const short8*)&xsh[cur][(rr*34 + cw)*8];
        }
        #pragma unroll
        for (int i = 0; i < 8; ++i) {
            short8 av = *(const short8*)&wsh[cur][((pjw*4 + lg)*128 + i*16 + ln)*8];
            #pragma unroll
            for (int jj = 0; jj < 4; ++jj)
                acc[i][jj] = __builtin_amdgcn_mfma_f32_16x16x32_bf16(
                                 av, bfr[jj], acc[i][jj], 0, 0, 0);
        }

        if (ch + 1 < 32) stage_write(cur ^ 1);
        __syncthreads();
    }

    #pragma unroll
    for (int i = 0; i < 8; ++i) {
        const f32x4 bv = *(const f32x4*)&bias[i*16 + lg*4];
        #pragma unroll
        for (int jj = 0; jj < 4; ++jj) {
            int arow  = q*2 + (jj >> 1);
            int b     = (jj & 1)*16 + ln;
            int i_out = 2*(a0 + arow) + pi;
            int j_out = 2*b + pjw;
            int o0    = i*16 + lg*4;
            int base  = ((n*128 + o0)*64 + i_out)*64 + j_out;
            #pragma unroll
            for (int r = 0; r < 4; ++r)
                out[base + r*4096] = acc[i][jj][r] + bv[r];
        }
    }
}

extern "C" void kernel_launch(void* const* d_in, const int* in_sizes, int n_in,
                              void* d_out, int out_size, void* d_ws, size_t ws_size,
                              hipStream_t stream) {
    const float* x    = (const float*)d_in[0];
    const float* W    = (const float*)d_in[1];
    const float* bias = (const float*)d_in[2];
    float* out        = (float*)d_out;

    const size_t wp2_bytes = (size_t)2 * WP_PI * 2;          // 1 MB
    const size_t xp_bytes  = (size_t)32 * XP_N * 2;          // ~20 MB
    if (ws_size >= wp2_bytes + xp_bytes) {
        unsigned short* wp2 = (unsigned short*)d_ws;
        unsigned short* xpp = (unsigned short*)((char*)d_ws + wp2_bytes);
        prepack_w2<<<128, 256, 0, stream>>>(W, wp2);
        prepack_x<<<dim3(34, 32), 256, 0, stream>>>(x, xpp);
        tconv_main<<<1024, 256, 0, stream>>>(xpp, wp2, bias, out);
    } else if (ws_size >= (size_t)4*4*128*256*2) {
        unsigned short* Wp = (unsigned short*)d_ws;
        prepack_w<<<128, 256, 0, stream>>>(W, Wp);
        tconv_mfma<true><<<256, 512, 0, stream>>>(x, W, Wp, bias, out);
    } else {
        tconv_mfma<false><<<256, 512, 0, stream>>>(x, W, nullptr, bias, out);
    }
}